// Round 10
// baseline (1296.786 us; speedup 1.0000x reference)
//
#include <hip/hip_runtime.h>

// Problem constants: T=512, N=512, I=256, H=256
#define kT 512
#define kN 512
#define kH 256
#define SBL 128  // scan blocks
#define SQ 4     // seqs per scan block

typedef float  f32x4  __attribute__((ext_vector_type(4)));
typedef __bf16 bf16x8 __attribute__((ext_vector_type(8)));
typedef __bf16 bf16x4 __attribute__((ext_vector_type(4)));
typedef __bf16 bf16x2 __attribute__((ext_vector_type(2)));

static __device__ __forceinline__ float sigm(float x) {
  float e = __builtin_amdgcn_exp2f(-1.4426950408889634f * x);
  return __builtin_amdgcn_rcpf(1.0f + e);
}
static __device__ __forceinline__ float tanh_fast(float x) {
  float e = __builtin_amdgcn_exp2f(-2.8853900817779268f * x);
  return fmaf(2.0f, __builtin_amdgcn_rcpf(1.0f + e), -1.0f);
}

// ---------------------------------------------------------------------------
// Phase 1: gi = x @ W_ih^T + b_ih (+ b_hh for r,z), bf16, layout v4
// ("reader-owns-chunk"): per (t, blk4 = seq>>2, w2) one contiguous 768-B
// chunk = 384 bf16:  chunk[(g*2+tp)*64 + c*4 + i] =
//   gi[seq = blk4*4 + i][col = g*256 + w2*32 + tp*16 + c]
// chunk base (elements) = ((t*128 + blk4)*8 + w2)*384
// Validated end-to-end in rounds 8-9.
// ---------------------------------------------------------------------------
__global__ __launch_bounds__(512) void gi_gemm(
    const float* __restrict__ x, const float* __restrict__ Wih,
    const float* __restrict__ bih, const float* __restrict__ bhh,
    __bf16* __restrict__ gis)
{
  __shared__ __align__(16) __bf16 Al[128][264];
  __shared__ __align__(16) __bf16 Bl[128][264];
  const int tid  = threadIdx.x;
  const int lane = tid & 63, w = tid >> 6;
  const int wm = w & 1, wn = w >> 1;            // 2 x 4 wave grid
  const int c = lane & 15, lg = lane >> 4;
  const long R0 = (long)blockIdx.x * 128;
  const int t  = (int)(R0 >> 9);
  const int n0 = (int)(R0 & 511);

  #pragma unroll
  for (int it = 0; it < 16; ++it) {
    int slot = tid + it * 512;
    int r  = slot >> 6;
    int kq = (slot & 63) * 4;
    float4 av = *(const float4*)(x + (R0 + r) * 256 + kq);
    bf16x4 a4 = {(__bf16)av.x, (__bf16)av.y, (__bf16)av.z, (__bf16)av.w};
    *(bf16x4*)(&Al[r][kq]) = a4;
  }

  for (int nb = 0; nb < 6; ++nb) {
    __syncthreads();
    #pragma unroll
    for (int it = 0; it < 16; ++it) {
      int slot = tid + it * 512;
      int r  = slot >> 6;
      int kq = (slot & 63) * 4;
      float4 bv = *(const float4*)(Wih + (long)(nb * 128 + r) * 256 + kq);
      bf16x4 b4 = {(__bf16)bv.x, (__bf16)bv.y, (__bf16)bv.z, (__bf16)bv.w};
      *(bf16x4*)(&Bl[r][kq]) = b4;
    }
    __syncthreads();

    const int gate = nb >> 1;
    f32x4 acc[4][2];
    #pragma unroll
    for (int nt = 0; nt < 2; ++nt) {
      int j = nb * 128 + wn * 32 + nt * 16 + c;
      float bv = bih[j] + (gate < 2 ? bhh[j] : 0.0f);
      #pragma unroll
      for (int mt = 0; mt < 4; ++mt) acc[mt][nt] = (f32x4){bv, bv, bv, bv};
    }

    #pragma unroll
    for (int ss = 0; ss < 8; ++ss) {
      bf16x8 af[4], bfr[2];
      #pragma unroll
      for (int mt = 0; mt < 4; ++mt)
        af[mt] = *(const bf16x8*)(&Al[wm * 64 + mt * 16 + c][ss * 32 + lg * 8]);
      #pragma unroll
      for (int nt = 0; nt < 2; ++nt)
        bfr[nt] = *(const bf16x8*)(&Bl[wn * 32 + nt * 16 + c][ss * 32 + lg * 8]);
      #pragma unroll
      for (int mt = 0; mt < 4; ++mt)
        #pragma unroll
        for (int nt = 0; nt < 2; ++nt)
          acc[mt][nt] = __builtin_amdgcn_mfma_f32_16x16x32_bf16(af[mt], bfr[nt], acc[mt][nt], 0, 0, 0);
    }

    // Epilogue v4: one bf16x4 (8 B) store per (mt, nt)
    const int w2g = (nb & 1) * 4 + wn;
    #pragma unroll
    for (int mt = 0; mt < 4; ++mt) {
      const int S16 = n0 + wm * 64 + mt * 16;
      const long blk4 = (S16 >> 2) + lg;
      #pragma unroll
      for (int nt = 0; nt < 2; ++nt) {
        bf16x4 v;
        #pragma unroll
        for (int i = 0; i < 4; ++i) v[i] = (__bf16)acc[mt][nt][i];
        long dest = (((long)t * 128 + blk4) * 8 + w2g) * 384 +
                    (gate * 2 + nt) * 64 + c * 4;
        *(bf16x4*)(gis + dest) = v;
      }
    }
  }
}

// ---------------------------------------------------------------------------
// Phase 2: scan. 128 blocks x 512 thr (8 waves, 2/SIMD). Register fit is
// proven (round 9: no spills): AGPR = exactly 128 (wfn+wfz, pinned once);
// accs pinned "+v"; r-gate W fp8 in LDS (own-slot readback, conflict-free).
// THIS ROUND: in-loop barrier = lgkmcnt(0) + raw s_barrier (NO vmcnt drain)
// so gi prefetch loads + out stores stay in flight across steps.
// ---------------------------------------------------------------------------
__global__ __attribute__((amdgpu_waves_per_eu(2, 2))) __launch_bounds__(512)
void gru_scan(
    const __bf16* __restrict__ gis, const float* __restrict__ h0,
    const float* __restrict__ done, const float* __restrict__ Whh,
    const float* __restrict__ bhh, float* __restrict__ out)
{
  __shared__ __align__(16) __bf16 hbuf[2][SQ * 256];          // 4 KB
  __shared__ __align__(16) unsigned char h8buf[2][SQ * 256];  // 2 KB
  __shared__ __align__(16) unsigned char wr8[8 * 16 * 64 * 8];// 64 KB
  __shared__ unsigned char doneL[kT * SQ];                    // 2 KB

  const int tid  = threadIdx.x;
  const int lane = tid & 63, w2 = tid >> 6;
  const int b   = blockIdx.x;
  const int nb4 = b * SQ;
  const int c = lane & 15, lg = lane >> 4;
  const int jh0 = w2 * 32 + c, jh1 = jh0 + 16;
  const int sr = c & 3;                  // dup row for M=4

  // --- W_hh: n,z bf16 -> 128 AGPRs (pinned once); r fp8 -> LDS (own slot)
  f32x4 wfn[16], wfz[16];
  #pragma unroll
  for (int tp = 0; tp < 2; ++tp) {
    const int jn = 512 + w2 * 32 + tp * 16 + c;
    const int jz = 256 + w2 * 32 + tp * 16 + c;
    const int jr =       w2 * 32 + tp * 16 + c;
    #pragma unroll
    for (int ss = 0; ss < 8; ++ss) {
      const int k0 = ss * 32 + lg * 8;
      float4 n0_ = *(const float4*)(Whh + (long)jn * 256 + k0);
      float4 n1_ = *(const float4*)(Whh + (long)jn * 256 + k0 + 4);
      bf16x8 vn = {(__bf16)n0_.x, (__bf16)n0_.y, (__bf16)n0_.z, (__bf16)n0_.w,
                   (__bf16)n1_.x, (__bf16)n1_.y, (__bf16)n1_.z, (__bf16)n1_.w};
      wfn[tp * 8 + ss] = __builtin_bit_cast(f32x4, vn);
      float4 z0 = *(const float4*)(Whh + (long)jz * 256 + k0);
      float4 z1 = *(const float4*)(Whh + (long)jz * 256 + k0 + 4);
      bf16x8 vz = {(__bf16)z0.x, (__bf16)z0.y, (__bf16)z0.z, (__bf16)z0.w,
                   (__bf16)z1.x, (__bf16)z1.y, (__bf16)z1.z, (__bf16)z1.w};
      wfz[tp * 8 + ss] = __builtin_bit_cast(f32x4, vz);
      float4 r0_ = *(const float4*)(Whh + (long)jr * 256 + k0);
      float4 r1_ = *(const float4*)(Whh + (long)jr * 256 + k0 + 4);
      int rl = __builtin_amdgcn_cvt_pk_fp8_f32(r0_.x, r0_.y, 0, 0);
      rl     = __builtin_amdgcn_cvt_pk_fp8_f32(r0_.z, r0_.w, rl, 1);
      int rh = __builtin_amdgcn_cvt_pk_fp8_f32(r1_.x, r1_.y, 0, 0);
      rh     = __builtin_amdgcn_cvt_pk_fp8_f32(r1_.z, r1_.w, rh, 1);
      int2 rp = {rl, rh};
      // LDS slot: ((w2*16 + tp*8 + ss)*64 + lane)*8 -- read back by same thread
      *(int2*)(&wr8[(((w2 * 16 + tp * 8 + ss) * 64) + lane) * 8]) = rp;
    }
  }
  #pragma unroll
  for (int i = 0; i < 16; ++i) {
    asm volatile("" : "+a"(wfn[i]));
    asm volatile("" : "+a"(wfz[i]));
  }
  const float bn0 = bhh[512 + jh0];
  const float bn1 = bhh[512 + jh1];

  // --- done -> LDS, shifted (row t = done[t+1]; last row 0)
  for (int idx = tid; idx < (kT - 1) * SQ; idx += 512) {
    int tt = idx >> 2, s = idx & 3;
    doneL[idx] = (unsigned char)(done[(long)(tt + 1) * kN + nb4 + s] != 0.0f);
  }
  if (tid < SQ) doneL[(kT - 1) * SQ + tid] = 0;

  // --- h init (scaled by 1-done[0]) into hbuf[0] + h8buf[0] + hold regs
  {
    const int s  = tid >> 7;            // 0..3
    const int k2 = (tid & 127) * 2;     // 0..254
    float sc = 1.0f - done[nb4 + s];
    const float* hp = h0 + (long)(nb4 + s) * 256 + k2;
    float f0 = hp[0] * sc, f1 = hp[1] * sc;
    bf16x2 v = {(__bf16)f0, (__bf16)f1};
    *(bf16x2*)(&hbuf[0][s * 256 + (((k2 * 2) ^ (s << 4)) >> 1)]) = v;
    int pk = __builtin_amdgcn_cvt_pk_fp8_f32(f0, f1, 0, 0);
    *(unsigned short*)(&h8buf[0][s * 256 + (k2 ^ (s << 3))]) = (unsigned short)(pk & 0xffff);
  }
  float hold[4][2];
  #pragma unroll
  for (int i = 0; i < 4; ++i) {
    float sc = 1.0f - done[nb4 + i];
    hold[i][0] = h0[(long)(nb4 + i) * 256 + jh0] * sc;
    hold[i][1] = h0[(long)(nb4 + i) * 256 + jh1] * sc;
  }
  __syncthreads();   // one-time full barrier after init

  // --- gi register prefetch: this (b, w2, c)'s chunk slice, one step ahead
  const long cstep = 128L * 8 * 384;                       // per-t chunk stride
  const __bf16* gcb = gis + ((long)b * 8 + w2) * 384 + c * 4;
  bf16x4 p00 = *(const bf16x4*)(gcb);
  bf16x4 p01 = *(const bf16x4*)(gcb + 64);
  bf16x4 p10 = *(const bf16x4*)(gcb + 128);
  bf16x4 p11 = *(const bf16x4*)(gcb + 192);
  bf16x4 pn0 = *(const bf16x4*)(gcb + 256);
  bf16x4 pn1 = *(const bf16x4*)(gcb + 320);

  const unsigned char* wrb = &wr8[w2 * 8192];   // this wave's r-W fragments

  #pragma unroll 1
  for (int t = 0; t < kT; ++t) {
    // (A) consume prefetched gi(t)
    bf16x4 q00 = p00, q01 = p01, q10 = p10, q11 = p11, qn0 = pn0, qn1 = pn1;
    unsigned du = *(const unsigned*)(&doneL[t * SQ]);

    // (B) issue gi(t+1) loads (clamped at tail; ~full step of latency cover)
    {
      const long tn = (t < kT - 1) ? (t + 1) : t;
      const __bf16* gc = gcb + tn * cstep;
      p00 = *(const bf16x4*)(gc);
      p01 = *(const bf16x4*)(gc + 64);
      p10 = *(const bf16x4*)(gc + 128);
      p11 = *(const bf16x4*)(gc + 192);
      pn0 = *(const bf16x4*)(gc + 256);
      pn1 = *(const bf16x4*)(gc + 320);
    }

    f32x4 ar0, ar1, az0, az1, an0, an1;
    #pragma unroll
    for (int i = 0; i < 4; ++i) {
      ar0[i] = (float)q00[i]; ar1[i] = (float)q01[i];
      az0[i] = (float)q10[i]; az1[i] = (float)q11[i];
    }
    an0 = (f32x4){bn0, bn0, bn0, bn0};
    an1 = (f32x4){bn1, bn1, bn1, bn1};
    // pin accs to ARCH VGPRs so AGPR demand stays exactly 128 (wfn+wfz)
    asm volatile("" : "+v"(ar0), "+v"(ar1), "+v"(az0), "+v"(az1), "+v"(an0), "+v"(an1));

    // (C) MFMA over K=256: A = h rows dup'd (sr); B: n,z from AGPR, r from LDS
    {
      const __bf16* hb = &hbuf[t & 1][0];
      const unsigned char* h8b = &h8buf[t & 1][0];
      #pragma unroll
      for (int ss = 0; ss < 8; ++ss) {
        int cb = (ss * 64 + lg * 16) ^ (sr << 4);
        bf16x8 afr = *(const bf16x8*)(hb + sr * 256 + (cb >> 1));
        long   a8  = *(const long*)(h8b + sr * 256 + ((ss * 32 + lg * 8) ^ (sr << 3)));
        long  br0 = *(const long*)(wrb + (ss * 64 + lane) * 8);
        long  br1 = *(const long*)(wrb + ((8 + ss) * 64 + lane) * 8);
        ar0 = __builtin_amdgcn_mfma_f32_16x16x32_fp8_fp8(a8, br0, ar0, 0, 0, 0);
        ar1 = __builtin_amdgcn_mfma_f32_16x16x32_fp8_fp8(a8, br1, ar1, 0, 0, 0);
        az0 = __builtin_amdgcn_mfma_f32_16x16x32_bf16(afr, __builtin_bit_cast(bf16x8, wfz[ss]),     az0, 0, 0, 0);
        az1 = __builtin_amdgcn_mfma_f32_16x16x32_bf16(afr, __builtin_bit_cast(bf16x8, wfz[8 + ss]), az1, 0, 0, 0);
        an0 = __builtin_amdgcn_mfma_f32_16x16x32_bf16(afr, __builtin_bit_cast(bf16x8, wfn[ss]),     an0, 0, 0, 0);
        an1 = __builtin_amdgcn_mfma_f32_16x16x32_bf16(afr, __builtin_bit_cast(bf16x8, wfn[8 + ss]), an1, 0, 0, 0);
      }
    }

    // (D) gates + update + stores (rows 0..3 real; lg==0 lanes store)
    {
      float* op = out + ((long)t * kN + nb4) * kH;
      __bf16* hw = &hbuf[(t & 1) ^ 1][0];
      unsigned char* h8w = &h8buf[(t & 1) ^ 1][0];
      #pragma unroll
      for (int i = 0; i < 4; ++i) {
        const float dn = (float)((du >> (8 * i)) & 255u);
        float r0 = sigm(ar0[i]);
        float r1 = sigm(ar1[i]);
        float z0 = sigm(az0[i]);
        float z1 = sigm(az1[i]);
        float n0v = tanh_fast((float)qn0[i] + r0 * an0[i]);
        float n1v = tanh_fast((float)qn1[i] + r1 * an1[i]);
        float hn0 = n0v + z0 * (hold[i][0] - n0v);
        float hn1 = n1v + z1 * (hold[i][1] - n1v);
        float hk0 = hn0 * (1.0f - dn);
        float hk1 = hn1 * (1.0f - dn);
        hold[i][0] = hk0;
        hold[i][1] = hk1;
        if (lg == 0) {
          op[(long)i * kH + jh0] = hn0;
          op[(long)i * kH + jh1] = hn1;
          hw[(i * 512 + ((jh0 * 2) ^ (i << 4))) >> 1] = (__bf16)hk0;
          hw[(i * 512 + ((jh1 * 2) ^ (i << 4))) >> 1] = (__bf16)hk1;
          int pk8 = __builtin_amdgcn_cvt_pk_fp8_f32(hk0, hk1, 0, 0);
          h8w[i * 256 + (jh0 ^ (i << 3))] = (unsigned char)(pk8 & 255);
          h8w[i * 256 + (jh1 ^ (i << 3))] = (unsigned char)((pk8 >> 8) & 255);
        }
      }
    }

    // (E) h(t+1) visible to all waves: LDS-only fence + raw barrier.
    // Raw s_barrier does NOT drain vmcnt -> gi prefetch + out stores stay
    // in flight (hbuf/h8buf are double-buffered; one barrier/step is sound).
    asm volatile("s_waitcnt lgkmcnt(0)" ::: "memory");
    asm volatile("s_barrier" ::: "memory");
  }

  // final hidden state (doneL last row = 0, so hold == h_T)
  if (lg == 0) {
    float* outF = out + (long)kT * kN * kH;
    #pragma unroll
    for (int i = 0; i < 4; ++i) {
      outF[(long)(nb4 + i) * kH + jh0] = hold[i][0];
      outF[(long)(nb4 + i) * kH + jh1] = hold[i][1];
    }
  }
}

// ---------------------------------------------------------------------------
// Fallback (ws too small): naive fp32.
// ---------------------------------------------------------------------------
__global__ __launch_bounds__(256) void gru_naive(
    const float* __restrict__ x, const float* __restrict__ h0,
    const float* __restrict__ done, const float* __restrict__ Wih,
    const float* __restrict__ Whh, const float* __restrict__ bih,
    const float* __restrict__ bhh, float* __restrict__ out)
{
  __shared__ float hsA[16][257];
  __shared__ float hsB[16][257];
  const int tid = threadIdx.x;
  const int b = blockIdx.x, nb = b * 16;
  for (int s = 0; s < 16; ++s)
    hsA[s][tid] = h0[(long)(nb + s) * 256 + tid] * (1.0f - done[nb + s]);
  __syncthreads();
  float (*hr)[257] = hsA;
  float (*hw)[257] = hsB;
  float* outF = out + (long)kT * kN * kH;
  for (int t = 0; t < kT; ++t) {
    for (int s = 0; s < 16; ++s) {
      const float* xr = x + ((long)t * kN + nb + s) * 256;
      float pr  = bih[tid] + bhh[tid];
      float pz  = bih[256 + tid] + bhh[256 + tid];
      float pnx = bih[512 + tid];
      float pnh = bhh[512 + tid];
      const float* wr = Wih + (long)tid * 256;
      const float* wz = Wih + (long)(256 + tid) * 256;
      const float* wn = Wih + (long)(512 + tid) * 256;
      const float* vr = Whh + (long)tid * 256;
      const float* vz = Whh + (long)(256 + tid) * 256;
      const float* vn = Whh + (long)(512 + tid) * 256;
      #pragma unroll 4
      for (int k = 0; k < 256; ++k) {
        float xv = xr[k], hv = hr[s][k];
        pr  = fmaf(xv, wr[k], pr);  pr  = fmaf(hv, vr[k], pr);
        pz  = fmaf(xv, wz[k], pz);  pz  = fmaf(hv, vz[k], pz);
        pnx = fmaf(xv, wn[k], pnx); pnh = fmaf(hv, vn[k], pnh);
      }
      float r = sigm(pr), z = sigm(pz);
      float n = tanh_fast(pnx + r * pnh);
      float ho = hr[s][tid];
      float hn = n + z * (ho - n);
      out[((long)t * kN + nb + s) * 256 + tid] = hn;
      if (t == kT - 1) outF[(long)(nb + s) * 256 + tid] = hn;
      float d = (t < kT - 1) ? done[(long)(t + 1) * kN + nb + s] : 0.0f;
      hw[s][tid] = hn * (1.0f - d);
    }
    __syncthreads();
    float (*tmp)[257] = hr; hr = hw; hw = tmp;
  }
}

extern "C" void kernel_launch(void* const* d_in, const int* in_sizes, int n_in,
                              void* d_out, int out_size, void* d_ws, size_t ws_size,
                              hipStream_t stream) {
  const float* x    = (const float*)d_in[0];
  const float* h0   = (const float*)d_in[1];
  const float* done = (const float*)d_in[2];
  const float* Wih  = (const float*)d_in[3];
  const float* Whh  = (const float*)d_in[4];
  const float* bih  = (const float*)d_in[5];
  const float* bhh  = (const float*)d_in[6];
  float* out = (float*)d_out;

  const size_t GI_BYTES = (size_t)kT * kN * 768 * 2;  // 402.7 MB bf16
  if (ws_size >= GI_BYTES) {
    __bf16* gis = (__bf16*)d_ws;
    hipLaunchKernelGGL(gi_gemm, dim3(2048), dim3(512), 0, stream, x, Wih, bih, bhh, gis);
    hipLaunchKernelGGL(gru_scan, dim3(SBL), dim3(512), 0, stream, gis, h0, done, Whh, bhh, out);
  } else {
    hipLaunchKernelGGL(gru_naive, dim3(32), dim3(256), 0, stream, x, h0, done, Wih, Whh, bih, bhh, out);
  }
}

// Round 11
// 1024.585 us; speedup vs baseline: 1.2657x; 1.2657x over previous
//
#include <hip/hip_runtime.h>

// Problem constants: T=512, N=512, I=256, H=256
#define kT 512
#define kN 512
#define kH 256
#define SBL 128  // scan blocks
#define SQ 4     // seqs per scan block

typedef float  f32x4  __attribute__((ext_vector_type(4)));
typedef __bf16 bf16x8 __attribute__((ext_vector_type(8)));
typedef __bf16 bf16x4 __attribute__((ext_vector_type(4)));
typedef __bf16 bf16x2 __attribute__((ext_vector_type(2)));

static __device__ __forceinline__ float sigm(float x) {
  float e = __builtin_amdgcn_exp2f(-1.4426950408889634f * x);
  return __builtin_amdgcn_rcpf(1.0f + e);
}
static __device__ __forceinline__ float tanh_fast(float x) {
  float e = __builtin_amdgcn_exp2f(-2.8853900817779268f * x);
  return fmaf(2.0f, __builtin_amdgcn_rcpf(1.0f + e), -1.0f);
}
// select element k (0..3) of a f32x4 with data-select cndmasks (no scratch)
static __device__ __forceinline__ float sel4(f32x4 v, int k) {
  float a = (k & 1) ? v[1] : v[0];
  float b = (k & 1) ? v[3] : v[2];
  return (k & 2) ? b : a;
}
static __device__ __forceinline__ float sel4b(bf16x4 v, int k) {
  float a = (k & 1) ? (float)v[1] : (float)v[0];
  float b = (k & 1) ? (float)v[3] : (float)v[2];
  return (k & 2) ? b : a;
}

// ---------------------------------------------------------------------------
// Phase 1: gi = x @ W_ih^T + b_ih (+ b_hh for r,z), bf16, layout v4
// ("reader-owns-chunk"): per (t, blk4 = seq>>2, w2) one contiguous 768-B
// chunk = 384 bf16:  chunk[(g*2+tp)*64 + c*4 + i] =
//   gi[seq = blk4*4 + i][col = g*256 + w2*32 + tp*16 + c]
// chunk base (elements) = ((t*128 + blk4)*8 + w2)*384
// Validated end-to-end in rounds 8-10.
// ---------------------------------------------------------------------------
__global__ __launch_bounds__(512) void gi_gemm(
    const float* __restrict__ x, const float* __restrict__ Wih,
    const float* __restrict__ bih, const float* __restrict__ bhh,
    __bf16* __restrict__ gis)
{
  __shared__ __align__(16) __bf16 Al[128][264];
  __shared__ __align__(16) __bf16 Bl[128][264];
  const int tid  = threadIdx.x;
  const int lane = tid & 63, w = tid >> 6;
  const int wm = w & 1, wn = w >> 1;            // 2 x 4 wave grid
  const int c = lane & 15, lg = lane >> 4;
  const long R0 = (long)blockIdx.x * 128;
  const int t  = (int)(R0 >> 9);
  const int n0 = (int)(R0 & 511);

  #pragma unroll
  for (int it = 0; it < 16; ++it) {
    int slot = tid + it * 512;
    int r  = slot >> 6;
    int kq = (slot & 63) * 4;
    float4 av = *(const float4*)(x + (R0 + r) * 256 + kq);
    bf16x4 a4 = {(__bf16)av.x, (__bf16)av.y, (__bf16)av.z, (__bf16)av.w};
    *(bf16x4*)(&Al[r][kq]) = a4;
  }

  for (int nb = 0; nb < 6; ++nb) {
    __syncthreads();
    #pragma unroll
    for (int it = 0; it < 16; ++it) {
      int slot = tid + it * 512;
      int r  = slot >> 6;
      int kq = (slot & 63) * 4;
      float4 bv = *(const float4*)(Wih + (long)(nb * 128 + r) * 256 + kq);
      bf16x4 b4 = {(__bf16)bv.x, (__bf16)bv.y, (__bf16)bv.z, (__bf16)bv.w};
      *(bf16x4*)(&Bl[r][kq]) = b4;
    }
    __syncthreads();

    const int gate = nb >> 1;
    f32x4 acc[4][2];
    #pragma unroll
    for (int nt = 0; nt < 2; ++nt) {
      int j = nb * 128 + wn * 32 + nt * 16 + c;
      float bv = bih[j] + (gate < 2 ? bhh[j] : 0.0f);
      #pragma unroll
      for (int mt = 0; mt < 4; ++mt) acc[mt][nt] = (f32x4){bv, bv, bv, bv};
    }

    #pragma unroll
    for (int ss = 0; ss < 8; ++ss) {
      bf16x8 af[4], bfr[2];
      #pragma unroll
      for (int mt = 0; mt < 4; ++mt)
        af[mt] = *(const bf16x8*)(&Al[wm * 64 + mt * 16 + c][ss * 32 + lg * 8]);
      #pragma unroll
      for (int nt = 0; nt < 2; ++nt)
        bfr[nt] = *(const bf16x8*)(&Bl[wn * 32 + nt * 16 + c][ss * 32 + lg * 8]);
      #pragma unroll
      for (int mt = 0; mt < 4; ++mt)
        #pragma unroll
        for (int nt = 0; nt < 2; ++nt)
          acc[mt][nt] = __builtin_amdgcn_mfma_f32_16x16x32_bf16(af[mt], bfr[nt], acc[mt][nt], 0, 0, 0);
    }

    // Epilogue v4: one bf16x4 (8 B) store per (mt, nt)
    const int w2g = (nb & 1) * 4 + wn;
    #pragma unroll
    for (int mt = 0; mt < 4; ++mt) {
      const int S16 = n0 + wm * 64 + mt * 16;
      const long blk4 = (S16 >> 2) + lg;
      #pragma unroll
      for (int nt = 0; nt < 2; ++nt) {
        bf16x4 v;
        #pragma unroll
        for (int i = 0; i < 4; ++i) v[i] = (__bf16)acc[mt][nt][i];
        long dest = (((long)t * 128 + blk4) * 8 + w2g) * 384 +
                    (gate * 2 + nt) * 64 + c * 4;
        *(bf16x4*)(gis + dest) = v;
      }
    }
  }
}

// ---------------------------------------------------------------------------
// Phase 2: scan. 128 blocks x 512 thr (8 waves, 2/SIMD). Register fit proven
// (rounds 9-10, no spills): AGPR = exactly 128 (wfn+wfz, pinned once); accs
// pinned "+v"; r-gate W fp8 in LDS (16-B tp-paired slots, b128 readback).
// THIS ROUND: gate-work dedup -- lg groups hold duplicate accs (M-tile row
// duplication), so each lane computes gates for row i=lg ONLY (2 h-elems,
// 12 trans/lane vs 48); all stores full-wave unmasked.
// ---------------------------------------------------------------------------
__global__ __attribute__((amdgpu_waves_per_eu(2, 2))) __launch_bounds__(512)
void gru_scan(
    const __bf16* __restrict__ gis, const float* __restrict__ h0,
    const float* __restrict__ done, const float* __restrict__ Whh,
    const float* __restrict__ bhh, float* __restrict__ out)
{
  __shared__ __align__(16) __bf16 hbuf[2][SQ * 256];          // 4 KB
  __shared__ __align__(16) unsigned char h8buf[2][SQ * 256];  // 2 KB
  __shared__ __align__(16) unsigned char wr8[8 * 8 * 64 * 16];// 64 KB
  __shared__ unsigned char doneL[kT * SQ];                    // 2 KB

  const int tid  = threadIdx.x;
  const int lane = tid & 63, w2 = tid >> 6;
  const int b   = blockIdx.x;
  const int nb4 = b * SQ;
  const int c = lane & 15, lg = lane >> 4;
  const int jh0 = w2 * 32 + c, jh1 = jh0 + 16;
  const int sr = c & 3;                  // dup row for M=4

  // --- W_hh: n,z bf16 -> 128 AGPRs (pinned once); r fp8 -> LDS
  // wr8 slot: ((w2*8 + ss)*64 + lane)*16 + tp*8  (tp halves paired -> b128)
  f32x4 wfn[16], wfz[16];
  #pragma unroll
  for (int tp = 0; tp < 2; ++tp) {
    const int jn = 512 + w2 * 32 + tp * 16 + c;
    const int jz = 256 + w2 * 32 + tp * 16 + c;
    const int jr =       w2 * 32 + tp * 16 + c;
    #pragma unroll
    for (int ss = 0; ss < 8; ++ss) {
      const int k0 = ss * 32 + lg * 8;
      float4 n0_ = *(const float4*)(Whh + (long)jn * 256 + k0);
      float4 n1_ = *(const float4*)(Whh + (long)jn * 256 + k0 + 4);
      bf16x8 vn = {(__bf16)n0_.x, (__bf16)n0_.y, (__bf16)n0_.z, (__bf16)n0_.w,
                   (__bf16)n1_.x, (__bf16)n1_.y, (__bf16)n1_.z, (__bf16)n1_.w};
      wfn[tp * 8 + ss] = __builtin_bit_cast(f32x4, vn);
      float4 z0 = *(const float4*)(Whh + (long)jz * 256 + k0);
      float4 z1 = *(const float4*)(Whh + (long)jz * 256 + k0 + 4);
      bf16x8 vz = {(__bf16)z0.x, (__bf16)z0.y, (__bf16)z0.z, (__bf16)z0.w,
                   (__bf16)z1.x, (__bf16)z1.y, (__bf16)z1.z, (__bf16)z1.w};
      wfz[tp * 8 + ss] = __builtin_bit_cast(f32x4, vz);
      float4 r0_ = *(const float4*)(Whh + (long)jr * 256 + k0);
      float4 r1_ = *(const float4*)(Whh + (long)jr * 256 + k0 + 4);
      int rl = __builtin_amdgcn_cvt_pk_fp8_f32(r0_.x, r0_.y, 0, 0);
      rl     = __builtin_amdgcn_cvt_pk_fp8_f32(r0_.z, r0_.w, rl, 1);
      int rh = __builtin_amdgcn_cvt_pk_fp8_f32(r1_.x, r1_.y, 0, 0);
      rh     = __builtin_amdgcn_cvt_pk_fp8_f32(r1_.z, r1_.w, rh, 1);
      int2 rp = {rl, rh};
      *(int2*)(&wr8[(((w2 * 8 + ss) * 64) + lane) * 16 + tp * 8]) = rp;
    }
  }
  #pragma unroll
  for (int i = 0; i < 16; ++i) {
    asm volatile("" : "+a"(wfn[i]));
    asm volatile("" : "+a"(wfz[i]));
  }
  const float bn0 = bhh[512 + jh0];
  const float bn1 = bhh[512 + jh1];

  // --- done -> LDS, shifted (row t = done[t+1]; last row 0)
  for (int idx = tid; idx < (kT - 1) * SQ; idx += 512) {
    int tt = idx >> 2, s = idx & 3;
    doneL[idx] = (unsigned char)(done[(long)(tt + 1) * kN + nb4 + s] != 0.0f);
  }
  if (tid < SQ) doneL[(kT - 1) * SQ + tid] = 0;

  // --- h init (scaled by 1-done[0]) into hbuf[0] + h8buf[0] + hold regs
  {
    const int s  = tid >> 7;            // 0..3
    const int k2 = (tid & 127) * 2;     // 0..254
    float sc = 1.0f - done[nb4 + s];
    const float* hp = h0 + (long)(nb4 + s) * 256 + k2;
    float f0 = hp[0] * sc, f1 = hp[1] * sc;
    bf16x2 v = {(__bf16)f0, (__bf16)f1};
    *(bf16x2*)(&hbuf[0][s * 256 + (((k2 * 2) ^ (s << 4)) >> 1)]) = v;
    int pk = __builtin_amdgcn_cvt_pk_fp8_f32(f0, f1, 0, 0);
    *(unsigned short*)(&h8buf[0][s * 256 + (k2 ^ (s << 3))]) = (unsigned short)(pk & 0xffff);
  }
  // per-lane state for row lg, cols jh0/jh1
  float hold0, hold1;
  {
    float sc = 1.0f - done[nb4 + lg];
    hold0 = h0[(long)(nb4 + lg) * 256 + jh0] * sc;
    hold1 = h0[(long)(nb4 + lg) * 256 + jh1] * sc;
  }
  __syncthreads();   // one-time full barrier after init

  // --- gi register prefetch: this (b, w2, c)'s chunk slice, one step ahead
  const long cstep = 128L * 8 * 384;                       // per-t chunk stride
  const __bf16* gcb = gis + ((long)b * 8 + w2) * 384 + c * 4;
  bf16x4 p00 = *(const bf16x4*)(gcb);
  bf16x4 p01 = *(const bf16x4*)(gcb + 64);
  bf16x4 p10 = *(const bf16x4*)(gcb + 128);
  bf16x4 p11 = *(const bf16x4*)(gcb + 192);
  bf16x4 pn0 = *(const bf16x4*)(gcb + 256);
  bf16x4 pn1 = *(const bf16x4*)(gcb + 320);

  const unsigned char* wrb = &wr8[w2 * 8192];   // this wave's r-W fragments

  #pragma unroll 1
  for (int t = 0; t < kT; ++t) {
    // (A) consume prefetched gi(t)
    bf16x4 q00 = p00, q01 = p01, q10 = p10, q11 = p11, qn0 = pn0, qn1 = pn1;
    unsigned du = *(const unsigned*)(&doneL[t * SQ]);

    // (B) issue gi(t+1) loads (clamped at tail; ~full step of latency cover)
    {
      const long tn = (t < kT - 1) ? (t + 1) : t;
      const __bf16* gc = gcb + tn * cstep;
      p00 = *(const bf16x4*)(gc);
      p01 = *(const bf16x4*)(gc + 64);
      p10 = *(const bf16x4*)(gc + 128);
      p11 = *(const bf16x4*)(gc + 192);
      pn0 = *(const bf16x4*)(gc + 256);
      pn1 = *(const bf16x4*)(gc + 320);
    }

    f32x4 ar0, ar1, az0, az1, an0, an1;
    #pragma unroll
    for (int i = 0; i < 4; ++i) {
      ar0[i] = (float)q00[i]; ar1[i] = (float)q01[i];
      az0[i] = (float)q10[i]; az1[i] = (float)q11[i];
    }
    an0 = (f32x4){bn0, bn0, bn0, bn0};
    an1 = (f32x4){bn1, bn1, bn1, bn1};
    // pin accs to ARCH VGPRs so AGPR demand stays exactly 128 (wfn+wfz)
    asm volatile("" : "+v"(ar0), "+v"(ar1), "+v"(az0), "+v"(az1), "+v"(an0), "+v"(an1));

    // (C) MFMA over K=256: A = h rows dup'd (sr); B: n,z from AGPR, r from LDS
    {
      const __bf16* hb = &hbuf[t & 1][0];
      const unsigned char* h8b = &h8buf[t & 1][0];
      #pragma unroll
      for (int ss = 0; ss < 8; ++ss) {
        int cb = (ss * 64 + lg * 16) ^ (sr << 4);
        bf16x8 afr = *(const bf16x8*)(hb + sr * 256 + (cb >> 1));
        long   a8  = *(const long*)(h8b + sr * 256 + ((ss * 32 + lg * 8) ^ (sr << 3)));
        int4  brp = *(const int4*)(wrb + (ss * 64 + lane) * 16);
        int2  b0i = {brp.x, brp.y};
        int2  b1i = {brp.z, brp.w};
        long  br0 = __builtin_bit_cast(long, b0i);
        long  br1 = __builtin_bit_cast(long, b1i);
        ar0 = __builtin_amdgcn_mfma_f32_16x16x32_fp8_fp8(a8, br0, ar0, 0, 0, 0);
        ar1 = __builtin_amdgcn_mfma_f32_16x16x32_fp8_fp8(a8, br1, ar1, 0, 0, 0);
        az0 = __builtin_amdgcn_mfma_f32_16x16x32_bf16(afr, __builtin_bit_cast(bf16x8, wfz[ss]),     az0, 0, 0, 0);
        az1 = __builtin_amdgcn_mfma_f32_16x16x32_bf16(afr, __builtin_bit_cast(bf16x8, wfz[8 + ss]), az1, 0, 0, 0);
        an0 = __builtin_amdgcn_mfma_f32_16x16x32_bf16(afr, __builtin_bit_cast(bf16x8, wfn[ss]),     an0, 0, 0, 0);
        an1 = __builtin_amdgcn_mfma_f32_16x16x32_bf16(afr, __builtin_bit_cast(bf16x8, wfn[8 + ss]), an1, 0, 0, 0);
      }
    }

    // (D) gates DEDUPLICATED: lg groups hold duplicate accs -> each lane
    // handles row i=lg only (2 h-elems). All stores full-wave, unmasked.
    {
      float* op = out + ((long)t * kN + nb4) * kH;
      __bf16* hw = &hbuf[(t & 1) ^ 1][0];
      unsigned char* h8w = &h8buf[(t & 1) ^ 1][0];
      const float dn = (float)((du >> (lg * 8)) & 255u);
      float r0 = sigm(sel4(ar0, lg));
      float r1 = sigm(sel4(ar1, lg));
      float z0 = sigm(sel4(az0, lg));
      float z1 = sigm(sel4(az1, lg));
      float n0v = tanh_fast(sel4b(qn0, lg) + r0 * sel4(an0, lg));
      float n1v = tanh_fast(sel4b(qn1, lg) + r1 * sel4(an1, lg));
      float hn0 = n0v + z0 * (hold0 - n0v);
      float hn1 = n1v + z1 * (hold1 - n1v);
      float hk0 = hn0 * (1.0f - dn);
      float hk1 = hn1 * (1.0f - dn);
      hold0 = hk0;
      hold1 = hk1;
      op[(long)lg * kH + jh0] = hn0;
      op[(long)lg * kH + jh1] = hn1;
      hw[(lg * 512 + ((jh0 * 2) ^ (lg << 4))) >> 1] = (__bf16)hk0;
      hw[(lg * 512 + ((jh1 * 2) ^ (lg << 4))) >> 1] = (__bf16)hk1;
      int pk8 = __builtin_amdgcn_cvt_pk_fp8_f32(hk0, hk1, 0, 0);
      h8w[lg * 256 + (jh0 ^ (lg << 3))] = (unsigned char)(pk8 & 255);
      h8w[lg * 256 + (jh1 ^ (lg << 3))] = (unsigned char)((pk8 >> 8) & 255);
    }

    // (E) h(t+1) visible to all waves: LDS-only fence + raw barrier
    // (gi prefetch + out stores stay in flight across the barrier).
    asm volatile("s_waitcnt lgkmcnt(0)" ::: "memory");
    asm volatile("s_barrier" ::: "memory");
  }

  // final hidden state (doneL last row = 0, so hold == h_T); full-wave store
  {
    float* outF = out + (long)kT * kN * kH;
    outF[(long)(nb4 + lg) * kH + jh0] = hold0;
    outF[(long)(nb4 + lg) * kH + jh1] = hold1;
  }
}

// ---------------------------------------------------------------------------
// Fallback (ws too small): naive fp32.
// ---------------------------------------------------------------------------
__global__ __launch_bounds__(256) void gru_naive(
    const float* __restrict__ x, const float* __restrict__ h0,
    const float* __restrict__ done, const float* __restrict__ Wih,
    const float* __restrict__ Whh, const float* __restrict__ bih,
    const float* __restrict__ bhh, float* __restrict__ out)
{
  __shared__ float hsA[16][257];
  __shared__ float hsB[16][257];
  const int tid = threadIdx.x;
  const int b = blockIdx.x, nb = b * 16;
  for (int s = 0; s < 16; ++s)
    hsA[s][tid] = h0[(long)(nb + s) * 256 + tid] * (1.0f - done[nb + s]);
  __syncthreads();
  float (*hr)[257] = hsA;
  float (*hw)[257] = hsB;
  float* outF = out + (long)kT * kN * kH;
  for (int t = 0; t < kT; ++t) {
    for (int s = 0; s < 16; ++s) {
      const float* xr = x + ((long)t * kN + nb + s) * 256;
      float pr  = bih[tid] + bhh[tid];
      float pz  = bih[256 + tid] + bhh[256 + tid];
      float pnx = bih[512 + tid];
      float pnh = bhh[512 + tid];
      const float* wr = Wih + (long)tid * 256;
      const float* wz = Wih + (long)(256 + tid) * 256;
      const float* wn = Wih + (long)(512 + tid) * 256;
      const float* vr = Whh + (long)tid * 256;
      const float* vz = Whh + (long)(256 + tid) * 256;
      const float* vn = Whh + (long)(512 + tid) * 256;
      #pragma unroll 4
      for (int k = 0; k < 256; ++k) {
        float xv = xr[k], hv = hr[s][k];
        pr  = fmaf(xv, wr[k], pr);  pr  = fmaf(hv, vr[k], pr);
        pz  = fmaf(xv, wz[k], pz);  pz  = fmaf(hv, vz[k], pz);
        pnx = fmaf(xv, wn[k], pnx); pnh = fmaf(hv, vn[k], pnh);
      }
      float r = sigm(pr), z = sigm(pz);
      float n = tanh_fast(pnx + r * pnh);
      float ho = hr[s][tid];
      float hn = n + z * (ho - n);
      out[((long)t * kN + nb + s) * 256 + tid] = hn;
      if (t == kT - 1) outF[(long)(nb + s) * 256 + tid] = hn;
      float d = (t < kT - 1) ? done[(long)(t + 1) * kN + nb + s] : 0.0f;
      hw[s][tid] = hn * (1.0f - d);
    }
    __syncthreads();
    float (*tmp)[257] = hr; hr = hw; hw = tmp;
  }
}

extern "C" void kernel_launch(void* const* d_in, const int* in_sizes, int n_in,
                              void* d_out, int out_size, void* d_ws, size_t ws_size,
                              hipStream_t stream) {
  const float* x    = (const float*)d_in[0];
  const float* h0   = (const float*)d_in[1];
  const float* done = (const float*)d_in[2];
  const float* Wih  = (const float*)d_in[3];
  const float* Whh  = (const float*)d_in[4];
  const float* bih  = (const float*)d_in[5];
  const float* bhh  = (const float*)d_in[6];
  float* out = (float*)d_out;

  const size_t GI_BYTES = (size_t)kT * kN * 768 * 2;  // 402.7 MB bf16
  if (ws_size >= GI_BYTES) {
    __bf16* gis = (__bf16*)d_ws;
    hipLaunchKernelGGL(gi_gemm, dim3(2048), dim3(512), 0, stream, x, Wih, bih, bhh, gis);
    hipLaunchKernelGGL(gru_scan, dim3(SBL), dim3(512), 0, stream, gis, h0, done, Whh, bhh, out);
  } else {
    hipLaunchKernelGGL(gru_naive, dim3(32), dim3(256), 0, stream, x, h0, done, Wih, Whh, bih, bhh, out);
  }
}

// Round 12
// 894.151 us; speedup vs baseline: 1.4503x; 1.1459x over previous
//
#include <hip/hip_runtime.h>

// Problem constants: T=512, N=512, I=256, H=256
#define kT 512
#define kN 512
#define kH 256
#define SBL 256  // scan blocks
#define SQ 2     // seqs per scan block

typedef float  f32x4  __attribute__((ext_vector_type(4)));
typedef __bf16 bf16x8 __attribute__((ext_vector_type(8)));
typedef __bf16 bf16x4 __attribute__((ext_vector_type(4)));
typedef __bf16 bf16x2 __attribute__((ext_vector_type(2)));

static __device__ __forceinline__ float sigm(float x) {
  float e = __builtin_amdgcn_exp2f(-1.4426950408889634f * x);
  return __builtin_amdgcn_rcpf(1.0f + e);
}
static __device__ __forceinline__ float tanh_fast(float x) {
  float e = __builtin_amdgcn_exp2f(-2.8853900817779268f * x);
  return fmaf(2.0f, __builtin_amdgcn_rcpf(1.0f + e), -1.0f);
}
static __device__ __forceinline__ float sel01(f32x4 v, int s) {
  return s ? v[1] : v[0];   // elems 2,3 are parity duplicates of 0,1
}

// ---------------------------------------------------------------------------
// Phase 1: gi = x @ W_ih^T + b_ih (+ b_hh for r,z), bf16, layout v5
// (seq-pair chunks): per (t, blk2 = seq>>1, w2) one contiguous 384-B chunk
// = 192 bf16:  chunk[(g*2+tp)*32 + c*2 + i] =
//   gi[seq = blk2*2 + i][col = g*256 + w2*32 + tp*16 + c],  i in {0,1}
// chunk base (elements) = ((t*256 + blk2)*8 + w2)*192
// ---------------------------------------------------------------------------
__global__ __launch_bounds__(512) void gi_gemm(
    const float* __restrict__ x, const float* __restrict__ Wih,
    const float* __restrict__ bih, const float* __restrict__ bhh,
    __bf16* __restrict__ gis)
{
  __shared__ __align__(16) __bf16 Al[128][264];
  __shared__ __align__(16) __bf16 Bl[128][264];
  const int tid  = threadIdx.x;
  const int lane = tid & 63, w = tid >> 6;
  const int wm = w & 1, wn = w >> 1;            // 2 x 4 wave grid
  const int c = lane & 15, lg = lane >> 4;
  const long R0 = (long)blockIdx.x * 128;
  const int t  = (int)(R0 >> 9);
  const int n0 = (int)(R0 & 511);

  #pragma unroll
  for (int it = 0; it < 16; ++it) {
    int slot = tid + it * 512;
    int r  = slot >> 6;
    int kq = (slot & 63) * 4;
    float4 av = *(const float4*)(x + (R0 + r) * 256 + kq);
    bf16x4 a4 = {(__bf16)av.x, (__bf16)av.y, (__bf16)av.z, (__bf16)av.w};
    *(bf16x4*)(&Al[r][kq]) = a4;
  }

  for (int nb = 0; nb < 6; ++nb) {
    __syncthreads();
    #pragma unroll
    for (int it = 0; it < 16; ++it) {
      int slot = tid + it * 512;
      int r  = slot >> 6;
      int kq = (slot & 63) * 4;
      float4 bv = *(const float4*)(Wih + (long)(nb * 128 + r) * 256 + kq);
      bf16x4 b4 = {(__bf16)bv.x, (__bf16)bv.y, (__bf16)bv.z, (__bf16)bv.w};
      *(bf16x4*)(&Bl[r][kq]) = b4;
    }
    __syncthreads();

    const int gate = nb >> 1;
    f32x4 acc[4][2];
    #pragma unroll
    for (int nt = 0; nt < 2; ++nt) {
      int j = nb * 128 + wn * 32 + nt * 16 + c;
      float bv = bih[j] + (gate < 2 ? bhh[j] : 0.0f);
      #pragma unroll
      for (int mt = 0; mt < 4; ++mt) acc[mt][nt] = (f32x4){bv, bv, bv, bv};
    }

    #pragma unroll
    for (int ss = 0; ss < 8; ++ss) {
      bf16x8 af[4], bfr[2];
      #pragma unroll
      for (int mt = 0; mt < 4; ++mt)
        af[mt] = *(const bf16x8*)(&Al[wm * 64 + mt * 16 + c][ss * 32 + lg * 8]);
      #pragma unroll
      for (int nt = 0; nt < 2; ++nt)
        bfr[nt] = *(const bf16x8*)(&Bl[wn * 32 + nt * 16 + c][ss * 32 + lg * 8]);
      #pragma unroll
      for (int mt = 0; mt < 4; ++mt)
        #pragma unroll
        for (int nt = 0; nt < 2; ++nt)
          acc[mt][nt] = __builtin_amdgcn_mfma_f32_16x16x32_bf16(af[mt], bfr[nt], acc[mt][nt], 0, 0, 0);
    }

    // Epilogue v5: two bf16x2 (4 B) stores per (mt, nt)
    const int w2g = (nb & 1) * 4 + wn;
    #pragma unroll
    for (int mt = 0; mt < 4; ++mt) {
      const int S16 = n0 + wm * 64 + mt * 16;
      const long blk2 = (S16 >> 1) + lg * 2;     // rows lg*4+{0,1}
      #pragma unroll
      for (int nt = 0; nt < 2; ++nt) {
        bf16x2 v0 = {(__bf16)acc[mt][nt][0], (__bf16)acc[mt][nt][1]};
        bf16x2 v1 = {(__bf16)acc[mt][nt][2], (__bf16)acc[mt][nt][3]};
        long base0 = (((long)t * 256 + blk2) * 8 + w2g) * 192 +
                     (gate * 2 + nt) * 32 + c * 2;
        long base1 = base0 + 8 * 192;            // blk2+1
        *(bf16x2*)(gis + base0) = v0;
        *(bf16x2*)(gis + base1) = v1;
      }
    }
  }
}

// ---------------------------------------------------------------------------
// Phase 2: scan. 256 blocks x 512 thr -> 2048 waves = 8/CU = 2 waves/SIMD
// (double the round-11 TLP; all 256 CUs used). Per-wave state unchanged
// (proven spill-free): AGPR = exactly 128 (wfn+wfz, pinned once); accs "+v";
// r-gate W fp8 in LDS. Each lane owns ONE h-element (s=lg&1, half=lg>>1).
// ---------------------------------------------------------------------------
__global__ __attribute__((amdgpu_waves_per_eu(2, 2))) __launch_bounds__(512)
void gru_scan(
    const __bf16* __restrict__ gis, const float* __restrict__ h0,
    const float* __restrict__ done, const float* __restrict__ Whh,
    const float* __restrict__ bhh, float* __restrict__ out)
{
  __shared__ __align__(16) __bf16 hbuf[2][SQ * 256];          // 2 KB
  __shared__ __align__(16) unsigned char h8buf[2][SQ * 256];  // 1 KB
  __shared__ __align__(16) unsigned char wr8[8 * 8 * 64 * 16];// 64 KB
  __shared__ unsigned char doneL[kT * SQ];                    // 1 KB

  const int tid  = threadIdx.x;
  const int lane = tid & 63, w2 = tid >> 6;
  const int b   = blockIdx.x;
  const int nb2 = b * SQ;
  const int c = lane & 15, lg = lane >> 4;
  const int jh0 = w2 * 32 + c, jh1 = jh0 + 16;
  const int sr = c & 1;                  // dup row for M=2
  const int s  = lg & 1;                 // owned seq row
  const int ch = lg >> 1;                // owned col half (0: jh0, 1: jh1)
  const int jh = w2 * 32 + ch * 16 + c;  // owned h column

  // --- W_hh: n,z bf16 -> 128 AGPRs (pinned once); r fp8 -> LDS
  // wr8 slot: ((w2*8 + ss)*64 + lane)*16 + tp*8  (tp halves paired -> b128)
  f32x4 wfn[16], wfz[16];
  #pragma unroll
  for (int tp = 0; tp < 2; ++tp) {
    const int jn = 512 + w2 * 32 + tp * 16 + c;
    const int jz = 256 + w2 * 32 + tp * 16 + c;
    const int jr =       w2 * 32 + tp * 16 + c;
    #pragma unroll
    for (int ss = 0; ss < 8; ++ss) {
      const int k0 = ss * 32 + lg * 8;
      float4 n0_ = *(const float4*)(Whh + (long)jn * 256 + k0);
      float4 n1_ = *(const float4*)(Whh + (long)jn * 256 + k0 + 4);
      bf16x8 vn = {(__bf16)n0_.x, (__bf16)n0_.y, (__bf16)n0_.z, (__bf16)n0_.w,
                   (__bf16)n1_.x, (__bf16)n1_.y, (__bf16)n1_.z, (__bf16)n1_.w};
      wfn[tp * 8 + ss] = __builtin_bit_cast(f32x4, vn);
      float4 z0 = *(const float4*)(Whh + (long)jz * 256 + k0);
      float4 z1 = *(const float4*)(Whh + (long)jz * 256 + k0 + 4);
      bf16x8 vz = {(__bf16)z0.x, (__bf16)z0.y, (__bf16)z0.z, (__bf16)z0.w,
                   (__bf16)z1.x, (__bf16)z1.y, (__bf16)z1.z, (__bf16)z1.w};
      wfz[tp * 8 + ss] = __builtin_bit_cast(f32x4, vz);
      float4 r0_ = *(const float4*)(Whh + (long)jr * 256 + k0);
      float4 r1_ = *(const float4*)(Whh + (long)jr * 256 + k0 + 4);
      int rl = __builtin_amdgcn_cvt_pk_fp8_f32(r0_.x, r0_.y, 0, 0);
      rl     = __builtin_amdgcn_cvt_pk_fp8_f32(r0_.z, r0_.w, rl, 1);
      int rh = __builtin_amdgcn_cvt_pk_fp8_f32(r1_.x, r1_.y, 0, 0);
      rh     = __builtin_amdgcn_cvt_pk_fp8_f32(r1_.z, r1_.w, rh, 1);
      int2 rp = {rl, rh};
      *(int2*)(&wr8[(((w2 * 8 + ss) * 64) + lane) * 16 + tp * 8]) = rp;
    }
  }
  #pragma unroll
  for (int i = 0; i < 16; ++i) {
    asm volatile("" : "+a"(wfn[i]));
    asm volatile("" : "+a"(wfz[i]));
  }
  const float bn0 = bhh[512 + jh0];
  const float bn1 = bhh[512 + jh1];

  // --- done -> LDS, shifted (row t = done[t+1]; last row 0)
  for (int idx = tid; idx < (kT - 1) * SQ; idx += 512) {
    int tt = idx >> 1, sq = idx & 1;
    doneL[idx] = (unsigned char)(done[(long)(tt + 1) * kN + nb2 + sq] != 0.0f);
  }
  if (tid < SQ) doneL[(kT - 1) * SQ + tid] = 0;

  // --- h init (scaled by 1-done[0]) into hbuf[0] + h8buf[0] + hold reg
  {
    const int sq = tid >> 8;            // 0..1
    const int k2 = (tid & 255) * 2;
    if (k2 < 256) {
      float sc = 1.0f - done[nb2 + sq];
      const float* hp = h0 + (long)(nb2 + sq) * 256 + k2;
      float f0 = hp[0] * sc, f1 = hp[1] * sc;
      bf16x2 v = {(__bf16)f0, (__bf16)f1};
      *(bf16x2*)(&hbuf[0][(sq * 512 + ((k2 * 2) ^ (sq << 4))) >> 1]) = v;
      int pk = __builtin_amdgcn_cvt_pk_fp8_f32(f0, f1, 0, 0);
      *(unsigned short*)(&h8buf[0][sq * 256 + (k2 ^ (sq << 3))]) = (unsigned short)(pk & 0xffff);
    }
  }
  float hold;
  {
    float sc = 1.0f - done[nb2 + s];
    hold = h0[(long)(nb2 + s) * 256 + jh] * sc;
  }
  __syncthreads();   // one-time full barrier after init

  // --- gi register prefetch: this (b, w2, c)'s chunk slice, one step ahead
  const long cstep = 256L * 8 * 192;                       // per-t chunk stride
  const __bf16* gcb = gis + ((long)b * 8 + w2) * 192 + c * 2;
  bf16x2 p00 = *(const bf16x2*)(gcb);
  bf16x2 p01 = *(const bf16x2*)(gcb + 32);
  bf16x2 p10 = *(const bf16x2*)(gcb + 64);
  bf16x2 p11 = *(const bf16x2*)(gcb + 96);
  bf16x2 pn0 = *(const bf16x2*)(gcb + 128);
  bf16x2 pn1 = *(const bf16x2*)(gcb + 160);

  const unsigned char* wrb = &wr8[w2 * 8192];   // this wave's r-W fragments

  #pragma unroll 1
  for (int t = 0; t < kT; ++t) {
    // (A) consume prefetched gi(t)
    bf16x2 q00 = p00, q01 = p01, q10 = p10, q11 = p11, qn0 = pn0, qn1 = pn1;
    unsigned short du2 = *(const unsigned short*)(&doneL[t * SQ]);

    // (B) issue gi(t+1) loads (clamped at tail; ~full step of latency cover)
    {
      const long tn = (t < kT - 1) ? (t + 1) : t;
      const __bf16* gc = gcb + tn * cstep;
      p00 = *(const bf16x2*)(gc);
      p01 = *(const bf16x2*)(gc + 32);
      p10 = *(const bf16x2*)(gc + 64);
      p11 = *(const bf16x2*)(gc + 96);
      pn0 = *(const bf16x2*)(gc + 128);
      pn1 = *(const bf16x2*)(gc + 160);
    }

    f32x4 ar0, ar1, az0, az1, an0, an1;
    {
      float r00 = (float)q00[0], r01 = (float)q00[1];
      float r10 = (float)q01[0], r11 = (float)q01[1];
      float z00 = (float)q10[0], z01 = (float)q10[1];
      float z10 = (float)q11[0], z11 = (float)q11[1];
      ar0 = (f32x4){r00, r01, r00, r01};
      ar1 = (f32x4){r10, r11, r10, r11};
      az0 = (f32x4){z00, z01, z00, z01};
      az1 = (f32x4){z10, z11, z10, z11};
    }
    an0 = (f32x4){bn0, bn0, bn0, bn0};
    an1 = (f32x4){bn1, bn1, bn1, bn1};
    // pin accs to ARCH VGPRs so AGPR demand stays exactly 128 (wfn+wfz)
    asm volatile("" : "+v"(ar0), "+v"(ar1), "+v"(az0), "+v"(az1), "+v"(an0), "+v"(an1));

    // (C) MFMA over K=256: A = h rows dup'd (sr); B: n,z from AGPR, r from LDS
    {
      const __bf16* hb = &hbuf[t & 1][0];
      const unsigned char* h8b = &h8buf[t & 1][0];
      #pragma unroll
      for (int ss = 0; ss < 8; ++ss) {
        int cb = (ss * 64 + lg * 16) ^ (sr << 4);
        bf16x8 afr = *(const bf16x8*)(hb + sr * 256 + (cb >> 1));
        long   a8  = *(const long*)(h8b + sr * 256 + ((ss * 32 + lg * 8) ^ (sr << 3)));
        int4  brp = *(const int4*)(wrb + (ss * 64 + lane) * 16);
        int2  b0i = {brp.x, brp.y};
        int2  b1i = {brp.z, brp.w};
        long  br0 = __builtin_bit_cast(long, b0i);
        long  br1 = __builtin_bit_cast(long, b1i);
        ar0 = __builtin_amdgcn_mfma_f32_16x16x32_fp8_fp8(a8, br0, ar0, 0, 0, 0);
        ar1 = __builtin_amdgcn_mfma_f32_16x16x32_fp8_fp8(a8, br1, ar1, 0, 0, 0);
        az0 = __builtin_amdgcn_mfma_f32_16x16x32_bf16(afr, __builtin_bit_cast(bf16x8, wfz[ss]),     az0, 0, 0, 0);
        az1 = __builtin_amdgcn_mfma_f32_16x16x32_bf16(afr, __builtin_bit_cast(bf16x8, wfz[8 + ss]), az1, 0, 0, 0);
        an0 = __builtin_amdgcn_mfma_f32_16x16x32_bf16(afr, __builtin_bit_cast(bf16x8, wfn[ss]),     an0, 0, 0, 0);
        an1 = __builtin_amdgcn_mfma_f32_16x16x32_bf16(afr, __builtin_bit_cast(bf16x8, wfn[8 + ss]), an1, 0, 0, 0);
      }
    }

    // (D) gates: each lane owns exactly one h-element (s, jh). Full-wave.
    {
      float* op = out + ((long)t * kN + nb2) * kH;
      __bf16* hw = &hbuf[(t & 1) ^ 1][0];
      unsigned char* h8w = &h8buf[(t & 1) ^ 1][0];
      const float dn = (float)((du2 >> (s * 8)) & 255u);
      float rv = sigm(ch ? sel01(ar1, s) : sel01(ar0, s));
      float zv = sigm(ch ? sel01(az1, s) : sel01(az0, s));
      float gn = ch ? (float)(s ? qn1[1] : qn1[0]) : (float)(s ? qn0[1] : qn0[0]);
      float hv = ch ? sel01(an1, s) : sel01(an0, s);
      float nv = tanh_fast(gn + rv * hv);
      float hn = nv + zv * (hold - nv);
      float hk = hn * (1.0f - dn);
      hold = hk;
      op[(long)s * kH + jh] = hn;
      hw[(s * 512 + ((jh * 2) ^ (s << 4))) >> 1] = (__bf16)hk;
      // fp8 h copy: single byte
      int pk8 = __builtin_amdgcn_cvt_pk_fp8_f32(hk, hk, 0, 0);
      h8w[s * 256 + (jh ^ (s << 3))] = (unsigned char)(pk8 & 255);
    }

    // (E) h(t+1) visible to all waves: LDS-only fence + raw barrier
    // (gi prefetch + out stores stay in flight across the barrier).
    asm volatile("s_waitcnt lgkmcnt(0)" ::: "memory");
    asm volatile("s_barrier" ::: "memory");
  }

  // final hidden state (doneL last row = 0, so hold == h_T); full-wave store
  {
    float* outF = out + (long)kT * kN * kH;
    outF[(long)(nb2 + s) * kH + jh] = hold;
  }
}

// ---------------------------------------------------------------------------
// Fallback (ws too small): naive fp32.
// ---------------------------------------------------------------------------
__global__ __launch_bounds__(256) void gru_naive(
    const float* __restrict__ x, const float* __restrict__ h0,
    const float* __restrict__ done, const float* __restrict__ Wih,
    const float* __restrict__ Whh, const float* __restrict__ bih,
    const float* __restrict__ bhh, float* __restrict__ out)
{
  __shared__ float hsA[16][257];
  __shared__ float hsB[16][257];
  const int tid = threadIdx.x;
  const int b = blockIdx.x, nb = b * 16;
  for (int s = 0; s < 16; ++s)
    hsA[s][tid] = h0[(long)(nb + s) * 256 + tid] * (1.0f - done[nb + s]);
  __syncthreads();
  float (*hr)[257] = hsA;
  float (*hw)[257] = hsB;
  float* outF = out + (long)kT * kN * kH;
  for (int t = 0; t < kT; ++t) {
    for (int s = 0; s < 16; ++s) {
      const float* xr = x + ((long)t * kN + nb + s) * 256;
      float pr  = bih[tid] + bhh[tid];
      float pz  = bih[256 + tid] + bhh[256 + tid];
      float pnx = bih[512 + tid];
      float pnh = bhh[512 + tid];
      const float* wr = Wih + (long)tid * 256;
      const float* wz = Wih + (long)(256 + tid) * 256;
      const float* wn = Wih + (long)(512 + tid) * 256;
      const float* vr = Whh + (long)tid * 256;
      const float* vz = Whh + (long)(256 + tid) * 256;
      const float* vn = Whh + (long)(512 + tid) * 256;
      #pragma unroll 4
      for (int k = 0; k < 256; ++k) {
        float xv = xr[k], hv = hr[s][k];
        pr  = fmaf(xv, wr[k], pr);  pr  = fmaf(hv, vr[k], pr);
        pz  = fmaf(xv, wz[k], pz);  pz  = fmaf(hv, vz[k], pz);
        pnx = fmaf(xv, wn[k], pnx); pnh = fmaf(hv, vn[k], pnh);
      }
      float r = sigm(pr), z = sigm(pz);
      float n = tanh_fast(pnx + r * pnh);
      float ho = hr[s][tid];
      float hn = n + z * (ho - n);
      out[((long)t * kN + nb + s) * 256 + tid] = hn;
      if (t == kT - 1) outF[(long)(nb + s) * 256 + tid] = hn;
      float d = (t < kT - 1) ? done[(long)(t + 1) * kN + nb + s] : 0.0f;
      hw[s][tid] = hn * (1.0f - d);
    }
    __syncthreads();
    float (*tmp)[257] = hr; hr = hw; hw = tmp;
  }
}

extern "C" void kernel_launch(void* const* d_in, const int* in_sizes, int n_in,
                              void* d_out, int out_size, void* d_ws, size_t ws_size,
                              hipStream_t stream) {
  const float* x    = (const float*)d_in[0];
  const float* h0   = (const float*)d_in[1];
  const float* done = (const float*)d_in[2];
  const float* Wih  = (const float*)d_in[3];
  const float* Whh  = (const float*)d_in[4];
  const float* bih  = (const float*)d_in[5];
  const float* bhh  = (const float*)d_in[6];
  float* out = (float*)d_out;

  const size_t GI_BYTES = (size_t)kT * kN * 768 * 2;  // 402.7 MB bf16
  if (ws_size >= GI_BYTES) {
    __bf16* gis = (__bf16*)d_ws;
    hipLaunchKernelGGL(gi_gemm, dim3(2048), dim3(512), 0, stream, x, Wih, bih, bhh, gis);
    hipLaunchKernelGGL(gru_scan, dim3(SBL), dim3(512), 0, stream, gis, h0, done, Whh, bhh, out);
  } else {
    hipLaunchKernelGGL(gru_naive, dim3(32), dim3(256), 0, stream, x, h0, done, Wih, Whh, bih, bhh, out);
  }
}

// Round 13
// 833.634 us; speedup vs baseline: 1.5556x; 1.0726x over previous
//
#include <hip/hip_runtime.h>

// Problem constants: T=512, N=512, I=256, H=256
#define kT 512
#define kN 512
#define kH 256
#define SBL 256  // scan blocks
#define SQ 2     // seqs per scan block

typedef float  f32x4  __attribute__((ext_vector_type(4)));
typedef __bf16 bf16x8 __attribute__((ext_vector_type(8)));
typedef __bf16 bf16x4 __attribute__((ext_vector_type(4)));
typedef __bf16 bf16x2 __attribute__((ext_vector_type(2)));

static __device__ __forceinline__ float sigm(float x) {
  float e = __builtin_amdgcn_exp2f(-1.4426950408889634f * x);
  return __builtin_amdgcn_rcpf(1.0f + e);
}
static __device__ __forceinline__ float tanh_fast(float x) {
  float e = __builtin_amdgcn_exp2f(-2.8853900817779268f * x);
  return fmaf(2.0f, __builtin_amdgcn_rcpf(1.0f + e), -1.0f);
}
static __device__ __forceinline__ float sel01(f32x4 v, int s) {
  return s ? v[1] : v[0];   // elems 2,3 are parity duplicates of 0,1
}

// ---------------------------------------------------------------------------
// Phase 1: gi = x @ W_ih^T + b_ih (+ b_hh for r,z), bf16, layout v5
// (seq-pair chunks): per (t, blk2 = seq>>1, w2) one contiguous 384-B chunk
// = 192 bf16:  chunk[(g*2+tp)*32 + c*2 + i] =
//   gi[seq = blk2*2 + i][col = g*256 + w2*32 + tp*16 + c],  i in {0,1}
// chunk base (elements) = ((t*256 + blk2)*8 + w2)*192
// Validated end-to-end in round 12.
// ---------------------------------------------------------------------------
__global__ __launch_bounds__(512) void gi_gemm(
    const float* __restrict__ x, const float* __restrict__ Wih,
    const float* __restrict__ bih, const float* __restrict__ bhh,
    __bf16* __restrict__ gis)
{
  __shared__ __align__(16) __bf16 Al[128][264];
  __shared__ __align__(16) __bf16 Bl[128][264];
  const int tid  = threadIdx.x;
  const int lane = tid & 63, w = tid >> 6;
  const int wm = w & 1, wn = w >> 1;            // 2 x 4 wave grid
  const int c = lane & 15, lg = lane >> 4;
  const long R0 = (long)blockIdx.x * 128;
  const int t  = (int)(R0 >> 9);
  const int n0 = (int)(R0 & 511);

  #pragma unroll
  for (int it = 0; it < 16; ++it) {
    int slot = tid + it * 512;
    int r  = slot >> 6;
    int kq = (slot & 63) * 4;
    float4 av = *(const float4*)(x + (R0 + r) * 256 + kq);
    bf16x4 a4 = {(__bf16)av.x, (__bf16)av.y, (__bf16)av.z, (__bf16)av.w};
    *(bf16x4*)(&Al[r][kq]) = a4;
  }

  for (int nb = 0; nb < 6; ++nb) {
    __syncthreads();
    #pragma unroll
    for (int it = 0; it < 16; ++it) {
      int slot = tid + it * 512;
      int r  = slot >> 6;
      int kq = (slot & 63) * 4;
      float4 bv = *(const float4*)(Wih + (long)(nb * 128 + r) * 256 + kq);
      bf16x4 b4 = {(__bf16)bv.x, (__bf16)bv.y, (__bf16)bv.z, (__bf16)bv.w};
      *(bf16x4*)(&Bl[r][kq]) = b4;
    }
    __syncthreads();

    const int gate = nb >> 1;
    f32x4 acc[4][2];
    #pragma unroll
    for (int nt = 0; nt < 2; ++nt) {
      int j = nb * 128 + wn * 32 + nt * 16 + c;
      float bv = bih[j] + (gate < 2 ? bhh[j] : 0.0f);
      #pragma unroll
      for (int mt = 0; mt < 4; ++mt) acc[mt][nt] = (f32x4){bv, bv, bv, bv};
    }

    #pragma unroll
    for (int ss = 0; ss < 8; ++ss) {
      bf16x8 af[4], bfr[2];
      #pragma unroll
      for (int mt = 0; mt < 4; ++mt)
        af[mt] = *(const bf16x8*)(&Al[wm * 64 + mt * 16 + c][ss * 32 + lg * 8]);
      #pragma unroll
      for (int nt = 0; nt < 2; ++nt)
        bfr[nt] = *(const bf16x8*)(&Bl[wn * 32 + nt * 16 + c][ss * 32 + lg * 8]);
      #pragma unroll
      for (int mt = 0; mt < 4; ++mt)
        #pragma unroll
        for (int nt = 0; nt < 2; ++nt)
          acc[mt][nt] = __builtin_amdgcn_mfma_f32_16x16x32_bf16(af[mt], bfr[nt], acc[mt][nt], 0, 0, 0);
    }

    // Epilogue v5: two bf16x2 (4 B) stores per (mt, nt)
    const int w2g = (nb & 1) * 4 + wn;
    #pragma unroll
    for (int mt = 0; mt < 4; ++mt) {
      const int S16 = n0 + wm * 64 + mt * 16;
      const long blk2 = (S16 >> 1) + lg * 2;     // rows lg*4+{0,1}
      #pragma unroll
      for (int nt = 0; nt < 2; ++nt) {
        bf16x2 v0 = {(__bf16)acc[mt][nt][0], (__bf16)acc[mt][nt][1]};
        bf16x2 v1 = {(__bf16)acc[mt][nt][2], (__bf16)acc[mt][nt][3]};
        long base0 = (((long)t * 256 + blk2) * 8 + w2g) * 192 +
                     (gate * 2 + nt) * 32 + c * 2;
        long base1 = base0 + 8 * 192;            // blk2+1
        *(bf16x2*)(gis + base0) = v0;
        *(bf16x2*)(gis + base1) = v1;
      }
    }
  }
}

// ---------------------------------------------------------------------------
// Phase 2: scan. 256 blocks x 512 thr -> 2 waves/SIMD on all 256 CUs.
// Register layout proven (rounds 9-12, spill-free): AGPR = exactly 128
// (wfn+wfz, pinned once); accs "+v"; r-gate W fp8 in LDS.
// THIS ROUND: conflict-free h layouts -- hbuf row stride 576 B (bank offset
// 16: row 0 banks b..b+15, row 1 the other 16 -> full 32-bank coverage),
// h8buf row stride 288 B (bank offset 8, disjoint per-row bank sets).
// No XOR swizzles. gi prefetch address = incremental pointer add.
// ---------------------------------------------------------------------------
__global__ __attribute__((amdgpu_waves_per_eu(2, 2))) __launch_bounds__(512)
void gru_scan(
    const __bf16* __restrict__ gis, const float* __restrict__ h0,
    const float* __restrict__ done, const float* __restrict__ Whh,
    const float* __restrict__ bhh, float* __restrict__ out)
{
  // row stride 288 elements (576 B) bf16; 288 bytes fp8. cols 0..255 + pad.
  __shared__ __align__(16) __bf16 hbuf[2][2 * 288];           // 2.25 KB
  __shared__ __align__(16) unsigned char h8buf[2][2 * 288];   // 1.13 KB
  __shared__ __align__(16) unsigned char wr8[8 * 8 * 64 * 16];// 64 KB
  __shared__ unsigned char doneL[kT * SQ];                    // 1 KB

  const int tid  = threadIdx.x;
  const int lane = tid & 63, w2 = tid >> 6;
  const int b   = blockIdx.x;
  const int nb2 = b * SQ;
  const int c = lane & 15, lg = lane >> 4;
  const int jh0 = w2 * 32 + c, jh1 = jh0 + 16;
  const int sr = c & 1;                  // dup row for M=2
  const int s  = lg & 1;                 // owned seq row
  const int ch = lg >> 1;                // owned col half (0: jh0, 1: jh1)
  const int jh = w2 * 32 + ch * 16 + c;  // owned h column

  // --- W_hh: n,z bf16 -> 128 AGPRs (pinned once); r fp8 -> LDS
  // wr8 slot: ((w2*8 + ss)*64 + lane)*16 + tp*8  (tp halves paired -> b128)
  f32x4 wfn[16], wfz[16];
  #pragma unroll
  for (int tp = 0; tp < 2; ++tp) {
    const int jn = 512 + w2 * 32 + tp * 16 + c;
    const int jz = 256 + w2 * 32 + tp * 16 + c;
    const int jr =       w2 * 32 + tp * 16 + c;
    #pragma unroll
    for (int ss = 0; ss < 8; ++ss) {
      const int k0 = ss * 32 + lg * 8;
      float4 n0_ = *(const float4*)(Whh + (long)jn * 256 + k0);
      float4 n1_ = *(const float4*)(Whh + (long)jn * 256 + k0 + 4);
      bf16x8 vn = {(__bf16)n0_.x, (__bf16)n0_.y, (__bf16)n0_.z, (__bf16)n0_.w,
                   (__bf16)n1_.x, (__bf16)n1_.y, (__bf16)n1_.z, (__bf16)n1_.w};
      wfn[tp * 8 + ss] = __builtin_bit_cast(f32x4, vn);
      float4 z0 = *(const float4*)(Whh + (long)jz * 256 + k0);
      float4 z1 = *(const float4*)(Whh + (long)jz * 256 + k0 + 4);
      bf16x8 vz = {(__bf16)z0.x, (__bf16)z0.y, (__bf16)z0.z, (__bf16)z0.w,
                   (__bf16)z1.x, (__bf16)z1.y, (__bf16)z1.z, (__bf16)z1.w};
      wfz[tp * 8 + ss] = __builtin_bit_cast(f32x4, vz);
      float4 r0_ = *(const float4*)(Whh + (long)jr * 256 + k0);
      float4 r1_ = *(const float4*)(Whh + (long)jr * 256 + k0 + 4);
      int rl = __builtin_amdgcn_cvt_pk_fp8_f32(r0_.x, r0_.y, 0, 0);
      rl     = __builtin_amdgcn_cvt_pk_fp8_f32(r0_.z, r0_.w, rl, 1);
      int rh = __builtin_amdgcn_cvt_pk_fp8_f32(r1_.x, r1_.y, 0, 0);
      rh     = __builtin_amdgcn_cvt_pk_fp8_f32(r1_.z, r1_.w, rh, 1);
      int2 rp = {rl, rh};
      *(int2*)(&wr8[(((w2 * 8 + ss) * 64) + lane) * 16 + tp * 8]) = rp;
    }
  }
  #pragma unroll
  for (int i = 0; i < 16; ++i) {
    asm volatile("" : "+a"(wfn[i]));
    asm volatile("" : "+a"(wfz[i]));
  }
  const float bn0 = bhh[512 + jh0];
  const float bn1 = bhh[512 + jh1];

  // --- done -> LDS, shifted (row t = done[t+1]; last row 0)
  for (int idx = tid; idx < (kT - 1) * SQ; idx += 512) {
    int tt = idx >> 1, sq = idx & 1;
    doneL[idx] = (unsigned char)(done[(long)(tt + 1) * kN + nb2 + sq] != 0.0f);
  }
  if (tid < SQ) doneL[(kT - 1) * SQ + tid] = 0;

  // --- h init (scaled by 1-done[0]) into hbuf[0] + h8buf[0] + hold reg
  if (tid < 256) {
    const int sq = tid >> 7;            // 0..1
    const int k2 = (tid & 127) * 2;     // 0..254
    float sc = 1.0f - done[nb2 + sq];
    const float* hp = h0 + (long)(nb2 + sq) * 256 + k2;
    float f0 = hp[0] * sc, f1 = hp[1] * sc;
    bf16x2 v = {(__bf16)f0, (__bf16)f1};
    *(bf16x2*)(&hbuf[0][sq * 288 + k2]) = v;
    int pk = __builtin_amdgcn_cvt_pk_fp8_f32(f0, f1, 0, 0);
    *(unsigned short*)(&h8buf[0][sq * 288 + k2]) = (unsigned short)(pk & 0xffff);
  }
  float hold;
  {
    float sc = 1.0f - done[nb2 + s];
    hold = h0[(long)(nb2 + s) * 256 + jh] * sc;
  }
  __syncthreads();   // one-time full barrier after init

  // --- gi register prefetch: this (b, w2, c)'s chunk slice, one step ahead
  const long cstep = 256L * 8 * 192;                       // per-t chunk stride
  const __bf16* gcb = gis + ((long)b * 8 + w2) * 192 + c * 2;
  const __bf16* gp = gcb;                                  // incremental ptr
  bf16x2 p00 = *(const bf16x2*)(gcb);
  bf16x2 p01 = *(const bf16x2*)(gcb + 32);
  bf16x2 p10 = *(const bf16x2*)(gcb + 64);
  bf16x2 p11 = *(const bf16x2*)(gcb + 96);
  bf16x2 pn0 = *(const bf16x2*)(gcb + 128);
  bf16x2 pn1 = *(const bf16x2*)(gcb + 160);

  const unsigned char* wrb = &wr8[w2 * 8192];   // this wave's r-W fragments

  #pragma unroll 1
  for (int t = 0; t < kT; ++t) {
    // (A) consume prefetched gi(t)
    bf16x2 q00 = p00, q01 = p01, q10 = p10, q11 = p11, qn0 = pn0, qn1 = pn1;
    unsigned short du2 = *(const unsigned short*)(&doneL[t * SQ]);

    // (B) issue gi(t+1) loads (incremental pointer; clamped dup at tail)
    {
      if (t < kT - 1) gp += cstep;
      p00 = *(const bf16x2*)(gp);
      p01 = *(const bf16x2*)(gp + 32);
      p10 = *(const bf16x2*)(gp + 64);
      p11 = *(const bf16x2*)(gp + 96);
      pn0 = *(const bf16x2*)(gp + 128);
      pn1 = *(const bf16x2*)(gp + 160);
    }

    f32x4 ar0, ar1, az0, az1, an0, an1;
    {
      float r00 = (float)q00[0], r01 = (float)q00[1];
      float r10 = (float)q01[0], r11 = (float)q01[1];
      float z00 = (float)q10[0], z01 = (float)q10[1];
      float z10 = (float)q11[0], z11 = (float)q11[1];
      ar0 = (f32x4){r00, r01, r00, r01};
      ar1 = (f32x4){r10, r11, r10, r11};
      az0 = (f32x4){z00, z01, z00, z01};
      az1 = (f32x4){z10, z11, z10, z11};
    }
    an0 = (f32x4){bn0, bn0, bn0, bn0};
    an1 = (f32x4){bn1, bn1, bn1, bn1};
    // pin accs to ARCH VGPRs so AGPR demand stays exactly 128 (wfn+wfz)
    asm volatile("" : "+v"(ar0), "+v"(ar1), "+v"(az0), "+v"(az1), "+v"(an0), "+v"(an1));

    // (C) MFMA over K=256: A = h rows dup'd (sr); B: n,z from AGPR, r from LDS
    {
      const __bf16* hb = &hbuf[t & 1][0];
      const unsigned char* h8b = &h8buf[t & 1][0];
      #pragma unroll
      for (int ss = 0; ss < 8; ++ss) {
        bf16x8 afr = *(const bf16x8*)(hb + sr * 288 + ss * 32 + lg * 8);
        long   a8  = *(const long*)(h8b + sr * 288 + ss * 32 + lg * 8);
        int4  brp = *(const int4*)(wrb + (ss * 64 + lane) * 16);
        int2  b0i = {brp.x, brp.y};
        int2  b1i = {brp.z, brp.w};
        long  br0 = __builtin_bit_cast(long, b0i);
        long  br1 = __builtin_bit_cast(long, b1i);
        ar0 = __builtin_amdgcn_mfma_f32_16x16x32_fp8_fp8(a8, br0, ar0, 0, 0, 0);
        ar1 = __builtin_amdgcn_mfma_f32_16x16x32_fp8_fp8(a8, br1, ar1, 0, 0, 0);
        az0 = __builtin_amdgcn_mfma_f32_16x16x32_bf16(afr, __builtin_bit_cast(bf16x8, wfz[ss]),     az0, 0, 0, 0);
        az1 = __builtin_amdgcn_mfma_f32_16x16x32_bf16(afr, __builtin_bit_cast(bf16x8, wfz[8 + ss]), az1, 0, 0, 0);
        an0 = __builtin_amdgcn_mfma_f32_16x16x32_bf16(afr, __builtin_bit_cast(bf16x8, wfn[ss]),     an0, 0, 0, 0);
        an1 = __builtin_amdgcn_mfma_f32_16x16x32_bf16(afr, __builtin_bit_cast(bf16x8, wfn[8 + ss]), an1, 0, 0, 0);
      }
    }

    // (D) gates: each lane owns exactly one h-element (s, jh). Full-wave.
    {
      float* op = out + ((long)t * kN + nb2) * kH;
      __bf16* hw = &hbuf[(t & 1) ^ 1][0];
      unsigned char* h8w = &h8buf[(t & 1) ^ 1][0];
      const float dn = (float)((du2 >> (s * 8)) & 255u);
      float rv = sigm(ch ? sel01(ar1, s) : sel01(ar0, s));
      float zv = sigm(ch ? sel01(az1, s) : sel01(az0, s));
      float gn = ch ? (float)(s ? qn1[1] : qn1[0]) : (float)(s ? qn0[1] : qn0[0]);
      float hv = ch ? sel01(an1, s) : sel01(an0, s);
      float nv = tanh_fast(gn + rv * hv);
      float hn = nv + zv * (hold - nv);
      float hk = hn * (1.0f - dn);
      hold = hk;
      op[(long)s * kH + jh] = hn;
      hw[s * 288 + jh] = (__bf16)hk;
      int pk8 = __builtin_amdgcn_cvt_pk_fp8_f32(hk, hk, 0, 0);
      h8w[s * 288 + jh] = (unsigned char)(pk8 & 255);
    }

    // (E) h(t+1) visible to all waves: LDS-only fence + raw barrier
    // (gi prefetch + out stores stay in flight across the barrier).
    asm volatile("s_waitcnt lgkmcnt(0)" ::: "memory");
    asm volatile("s_barrier" ::: "memory");
  }

  // final hidden state (doneL last row = 0, so hold == h_T); full-wave store
  {
    float* outF = out + (long)kT * kN * kH;
    outF[(long)(nb2 + s) * kH + jh] = hold;
  }
}

// ---------------------------------------------------------------------------
// Fallback (ws too small): naive fp32.
// ---------------------------------------------------------------------------
__global__ __launch_bounds__(256) void gru_naive(
    const float* __restrict__ x, const float* __restrict__ h0,
    const float* __restrict__ done, const float* __restrict__ Wih,
    const float* __restrict__ Whh, const float* __restrict__ bih,
    const float* __restrict__ bhh, float* __restrict__ out)
{
  __shared__ float hsA[16][257];
  __shared__ float hsB[16][257];
  const int tid = threadIdx.x;
  const int b = blockIdx.x, nb = b * 16;
  for (int s = 0; s < 16; ++s)
    hsA[s][tid] = h0[(long)(nb + s) * 256 + tid] * (1.0f - done[nb + s]);
  __syncthreads();
  float (*hr)[257] = hsA;
  float (*hw)[257] = hsB;
  float* outF = out + (long)kT * kN * kH;
  for (int t = 0; t < kT; ++t) {
    for (int s = 0; s < 16; ++s) {
      const float* xr = x + ((long)t * kN + nb + s) * 256;
      float pr  = bih[tid] + bhh[tid];
      float pz  = bih[256 + tid] + bhh[256 + tid];
      float pnx = bih[512 + tid];
      float pnh = bhh[512 + tid];
      const float* wr = Wih + (long)tid * 256;
      const float* wz = Wih + (long)(256 + tid) * 256;
      const float* wn = Wih + (long)(512 + tid) * 256;
      const float* vr = Whh + (long)tid * 256;
      const float* vz = Whh + (long)(256 + tid) * 256;
      const float* vn = Whh + (long)(512 + tid) * 256;
      #pragma unroll 4
      for (int k = 0; k < 256; ++k) {
        float xv = xr[k], hv = hr[s][k];
        pr  = fmaf(xv, wr[k], pr);  pr  = fmaf(hv, vr[k], pr);
        pz  = fmaf(xv, wz[k], pz);  pz  = fmaf(hv, vz[k], pz);
        pnx = fmaf(xv, wn[k], pnx); pnh = fmaf(hv, vn[k], pnh);
      }
      float r = sigm(pr), z = sigm(pz);
      float n = tanh_fast(pnx + r * pnh);
      float ho = hr[s][tid];
      float hn = n + z * (ho - n);
      out[((long)t * kN + nb + s) * 256 + tid] = hn;
      if (t == kT - 1) outF[(long)(nb + s) * 256 + tid] = hn;
      float d = (t < kT - 1) ? done[(long)(t + 1) * kN + nb + s] : 0.0f;
      hw[s][tid] = hn * (1.0f - d);
    }
    __syncthreads();
    float (*tmp)[257] = hr; hr = hw; hw = tmp;
  }
}

extern "C" void kernel_launch(void* const* d_in, const int* in_sizes, int n_in,
                              void* d_out, int out_size, void* d_ws, size_t ws_size,
                              hipStream_t stream) {
  const float* x    = (const float*)d_in[0];
  const float* h0   = (const float*)d_in[1];
  const float* done = (const float*)d_in[2];
  const float* Wih  = (const float*)d_in[3];
  const float* Whh  = (const float*)d_in[4];
  const float* bih  = (const float*)d_in[5];
  const float* bhh  = (const float*)d_in[6];
  float* out = (float*)d_out;

  const size_t GI_BYTES = (size_t)kT * kN * 768 * 2;  // 402.7 MB bf16
  if (ws_size >= GI_BYTES) {
    __bf16* gis = (__bf16*)d_ws;
    hipLaunchKernelGGL(gi_gemm, dim3(2048), dim3(512), 0, stream, x, Wih, bih, bhh, gis);
    hipLaunchKernelGGL(gru_scan, dim3(SBL), dim3(512), 0, stream, gis, h0, done, Whh, bhh, out);
  } else {
    hipLaunchKernelGGL(gru_naive, dim3(32), dim3(256), 0, stream, x, h0, done, Wih, Whh, bih, bhh, out);
  }
}

// Round 14
// 822.547 us; speedup vs baseline: 1.5765x; 1.0135x over previous
//
#include <hip/hip_runtime.h>

// Problem constants: T=512, N=512, I=256, H=256
#define kT 512
#define kN 512
#define kH 256
#define SBL 256  // scan blocks
#define SQ 2     // seqs per scan block

typedef float  f32x4  __attribute__((ext_vector_type(4)));
typedef __bf16 bf16x8 __attribute__((ext_vector_type(8)));
typedef __bf16 bf16x4 __attribute__((ext_vector_type(4)));
typedef __bf16 bf16x2 __attribute__((ext_vector_type(2)));

static __device__ __forceinline__ float sigm(float x) {
  float e = __builtin_amdgcn_exp2f(-1.4426950408889634f * x);
  return __builtin_amdgcn_rcpf(1.0f + e);
}
static __device__ __forceinline__ float tanh_fast(float x) {
  float e = __builtin_amdgcn_exp2f(-2.8853900817779268f * x);
  return fmaf(2.0f, __builtin_amdgcn_rcpf(1.0f + e), -1.0f);
}
static __device__ __forceinline__ float sel01(f32x4 v, int s) {
  return s ? v[1] : v[0];   // elems 2,3 are parity duplicates of 0,1
}

// ---------------------------------------------------------------------------
// Phase 1: gi = x @ W_ih^T + b_ih (+ b_hh for r,z), bf16, layout v5
// (seq-pair chunks): per (t, blk2 = seq>>1, w2) one contiguous 384-B chunk
// = 192 bf16:  chunk[(g*2+tp)*32 + c*2 + i] =
//   gi[seq = blk2*2 + i][col = g*256 + w2*32 + tp*16 + c],  i in {0,1}
// chunk base (elements) = ((t*256 + blk2)*8 + w2)*192
// Validated end-to-end in rounds 12-13. UNCHANGED this round.
// ---------------------------------------------------------------------------
__global__ __launch_bounds__(512) void gi_gemm(
    const float* __restrict__ x, const float* __restrict__ Wih,
    const float* __restrict__ bih, const float* __restrict__ bhh,
    __bf16* __restrict__ gis)
{
  __shared__ __align__(16) __bf16 Al[128][264];
  __shared__ __align__(16) __bf16 Bl[128][264];
  const int tid  = threadIdx.x;
  const int lane = tid & 63, w = tid >> 6;
  const int wm = w & 1, wn = w >> 1;            // 2 x 4 wave grid
  const int c = lane & 15, lg = lane >> 4;
  const long R0 = (long)blockIdx.x * 128;
  const int t  = (int)(R0 >> 9);
  const int n0 = (int)(R0 & 511);

  #pragma unroll
  for (int it = 0; it < 16; ++it) {
    int slot = tid + it * 512;
    int r  = slot >> 6;
    int kq = (slot & 63) * 4;
    float4 av = *(const float4*)(x + (R0 + r) * 256 + kq);
    bf16x4 a4 = {(__bf16)av.x, (__bf16)av.y, (__bf16)av.z, (__bf16)av.w};
    *(bf16x4*)(&Al[r][kq]) = a4;
  }

  for (int nb = 0; nb < 6; ++nb) {
    __syncthreads();
    #pragma unroll
    for (int it = 0; it < 16; ++it) {
      int slot = tid + it * 512;
      int r  = slot >> 6;
      int kq = (slot & 63) * 4;
      float4 bv = *(const float4*)(Wih + (long)(nb * 128 + r) * 256 + kq);
      bf16x4 b4 = {(__bf16)bv.x, (__bf16)bv.y, (__bf16)bv.z, (__bf16)bv.w};
      *(bf16x4*)(&Bl[r][kq]) = b4;
    }
    __syncthreads();

    const int gate = nb >> 1;
    f32x4 acc[4][2];
    #pragma unroll
    for (int nt = 0; nt < 2; ++nt) {
      int j = nb * 128 + wn * 32 + nt * 16 + c;
      float bv = bih[j] + (gate < 2 ? bhh[j] : 0.0f);
      #pragma unroll
      for (int mt = 0; mt < 4; ++mt) acc[mt][nt] = (f32x4){bv, bv, bv, bv};
    }

    #pragma unroll
    for (int ss = 0; ss < 8; ++ss) {
      bf16x8 af[4], bfr[2];
      #pragma unroll
      for (int mt = 0; mt < 4; ++mt)
        af[mt] = *(const bf16x8*)(&Al[wm * 64 + mt * 16 + c][ss * 32 + lg * 8]);
      #pragma unroll
      for (int nt = 0; nt < 2; ++nt)
        bfr[nt] = *(const bf16x8*)(&Bl[wn * 32 + nt * 16 + c][ss * 32 + lg * 8]);
      #pragma unroll
      for (int mt = 0; mt < 4; ++mt)
        #pragma unroll
        for (int nt = 0; nt < 2; ++nt)
          acc[mt][nt] = __builtin_amdgcn_mfma_f32_16x16x32_bf16(af[mt], bfr[nt], acc[mt][nt], 0, 0, 0);
    }

    // Epilogue v5: two bf16x2 (4 B) stores per (mt, nt)
    const int w2g = (nb & 1) * 4 + wn;
    #pragma unroll
    for (int mt = 0; mt < 4; ++mt) {
      const int S16 = n0 + wm * 64 + mt * 16;
      const long blk2 = (S16 >> 1) + lg * 2;     // rows lg*4+{0,1}
      #pragma unroll
      for (int nt = 0; nt < 2; ++nt) {
        bf16x2 v0 = {(__bf16)acc[mt][nt][0], (__bf16)acc[mt][nt][1]};
        bf16x2 v1 = {(__bf16)acc[mt][nt][2], (__bf16)acc[mt][nt][3]};
        long base0 = (((long)t * 256 + blk2) * 8 + w2g) * 192 +
                     (gate * 2 + nt) * 32 + c * 2;
        long base1 = base0 + 8 * 192;            // blk2+1
        *(bf16x2*)(gis + base0) = v0;
        *(bf16x2*)(gis + base1) = v1;
      }
    }
  }
}

// ---------------------------------------------------------------------------
// Phase 2: scan. 256 blocks x 512 thr -> 2 waves/SIMD on all 256 CUs.
// Proven pieces unchanged: AGPR = exactly 128 (wfn+wfz, pinned once);
// r-gate W fp8 in LDS; conflict-free 576/288-B-stride h layouts (0 conflicts).
// THIS ROUND (VALU cut): gi consumed as 3 SCALARS per lane in the gate phase
// (not vectors into acc); accumulators born from MFMA via loop-invariant
// C-in (Z for r,z; BN bias for n) -- zero per-step acc-init VALU; out ptr
// incremental; per-iteration acc pins dropped (AGPRs full -> accs arch).
// ---------------------------------------------------------------------------
__global__ __attribute__((amdgpu_waves_per_eu(2, 2))) __launch_bounds__(512)
void gru_scan(
    const __bf16* __restrict__ gis, const float* __restrict__ h0,
    const float* __restrict__ done, const float* __restrict__ Whh,
    const float* __restrict__ bhh, float* __restrict__ out)
{
  // row stride 288 elements (576 B) bf16; 288 bytes fp8.
  __shared__ __align__(16) __bf16 hbuf[2][2 * 288];           // 2.25 KB
  __shared__ __align__(16) unsigned char h8buf[2][2 * 288];   // 1.13 KB
  __shared__ __align__(16) unsigned char wr8[8 * 8 * 64 * 16];// 64 KB
  __shared__ unsigned char doneL[kT * SQ];                    // 1 KB

  const int tid  = threadIdx.x;
  const int lane = tid & 63, w2 = tid >> 6;
  const int b   = blockIdx.x;
  const int nb2 = b * SQ;
  const int c = lane & 15, lg = lane >> 4;
  const int jh0 = w2 * 32 + c, jh1 = jh0 + 16;
  const int sr = c & 1;                  // dup row for M=2
  const int s  = lg & 1;                 // owned seq row
  const int ch = lg >> 1;                // owned col half (0: jh0, 1: jh1)
  const int jh = w2 * 32 + ch * 16 + c;  // owned h column

  // --- W_hh: n,z bf16 -> 128 AGPRs (pinned once); r fp8 -> LDS
  // wr8 slot: ((w2*8 + ss)*64 + lane)*16 + tp*8  (tp halves paired -> b128)
  f32x4 wfn[16], wfz[16];
  #pragma unroll
  for (int tp = 0; tp < 2; ++tp) {
    const int jn = 512 + w2 * 32 + tp * 16 + c;
    const int jz = 256 + w2 * 32 + tp * 16 + c;
    const int jr =       w2 * 32 + tp * 16 + c;
    #pragma unroll
    for (int ss = 0; ss < 8; ++ss) {
      const int k0 = ss * 32 + lg * 8;
      float4 n0_ = *(const float4*)(Whh + (long)jn * 256 + k0);
      float4 n1_ = *(const float4*)(Whh + (long)jn * 256 + k0 + 4);
      bf16x8 vn = {(__bf16)n0_.x, (__bf16)n0_.y, (__bf16)n0_.z, (__bf16)n0_.w,
                   (__bf16)n1_.x, (__bf16)n1_.y, (__bf16)n1_.z, (__bf16)n1_.w};
      wfn[tp * 8 + ss] = __builtin_bit_cast(f32x4, vn);
      float4 z0 = *(const float4*)(Whh + (long)jz * 256 + k0);
      float4 z1 = *(const float4*)(Whh + (long)jz * 256 + k0 + 4);
      bf16x8 vz = {(__bf16)z0.x, (__bf16)z0.y, (__bf16)z0.z, (__bf16)z0.w,
                   (__bf16)z1.x, (__bf16)z1.y, (__bf16)z1.z, (__bf16)z1.w};
      wfz[tp * 8 + ss] = __builtin_bit_cast(f32x4, vz);
      float4 r0_ = *(const float4*)(Whh + (long)jr * 256 + k0);
      float4 r1_ = *(const float4*)(Whh + (long)jr * 256 + k0 + 4);
      int rl = __builtin_amdgcn_cvt_pk_fp8_f32(r0_.x, r0_.y, 0, 0);
      rl     = __builtin_amdgcn_cvt_pk_fp8_f32(r0_.z, r0_.w, rl, 1);
      int rh = __builtin_amdgcn_cvt_pk_fp8_f32(r1_.x, r1_.y, 0, 0);
      rh     = __builtin_amdgcn_cvt_pk_fp8_f32(r1_.z, r1_.w, rh, 1);
      int2 rp = {rl, rh};
      *(int2*)(&wr8[(((w2 * 8 + ss) * 64) + lane) * 16 + tp * 8]) = rp;
    }
  }
  #pragma unroll
  for (int i = 0; i < 16; ++i) {
    asm volatile("" : "+a"(wfn[i]));
    asm volatile("" : "+a"(wfz[i]));
  }

  // --- done -> LDS, shifted (row t = done[t+1]; last row 0)
  for (int idx = tid; idx < (kT - 1) * SQ; idx += 512) {
    int tt = idx >> 1, sq = idx & 1;
    doneL[idx] = (unsigned char)(done[(long)(tt + 1) * kN + nb2 + sq] != 0.0f);
  }
  if (tid < SQ) doneL[(kT - 1) * SQ + tid] = 0;

  // --- h init (scaled by 1-done[0]) into hbuf[0] + h8buf[0] + hold reg
  if (tid < 256) {
    const int sq = tid >> 7;            // 0..1
    const int k2 = (tid & 127) * 2;     // 0..254
    float sc = 1.0f - done[nb2 + sq];
    const float* hp = h0 + (long)(nb2 + sq) * 256 + k2;
    float f0 = hp[0] * sc, f1 = hp[1] * sc;
    bf16x2 v = {(__bf16)f0, (__bf16)f1};
    *(bf16x2*)(&hbuf[0][sq * 288 + k2]) = v;
    int pk = __builtin_amdgcn_cvt_pk_fp8_f32(f0, f1, 0, 0);
    *(unsigned short*)(&h8buf[0][sq * 288 + k2]) = (unsigned short)(pk & 0xffff);
  }
  float hold;
  {
    float sc = 1.0f - done[nb2 + s];
    hold = h0[(long)(nb2 + s) * 256 + jh] * sc;
  }
  __syncthreads();   // one-time full barrier after init

  // --- loop-invariant MFMA C-in vectors: Z (r,z gates), BN0/BN1 (n bias)
  const float bn0 = bhh[512 + jh0];
  const float bn1 = bhh[512 + jh1];
  const f32x4 Z   = (f32x4){0.0f, 0.0f, 0.0f, 0.0f};
  const f32x4 BN0 = (f32x4){bn0, bn0, bn0, bn0};
  const f32x4 BN1 = (f32x4){bn1, bn1, bn1, bn1};

  // --- gi register prefetch: 3 SCALARS per lane (its own r,z,n), 1 step ahead
  const long cstep = 256L * 8 * 192;                       // per-t chunk stride
  const __bf16* gpl = gis + ((long)b * 8 + w2) * 192 + (ch * 32 + c * 2 + s);
  __bf16 prn = gpl[0];    // r-gate gi (b_ih+b_hh folded)
  __bf16 pzn = gpl[64];   // z-gate gi (b_ih+b_hh folded)
  __bf16 pnn = gpl[128];  // n-gate gi (b_ih folded)

  const unsigned char* wrb = &wr8[w2 * 8192];   // this wave's r-W fragments
  float* op = out + ((long)nb2 + s) * kH + jh;  // incremental out pointer

  #pragma unroll 1
  for (int t = 0; t < kT; ++t) {
    // (A) consume prefetched gi(t) scalars
    float gir = (float)prn, giz = (float)pzn, gin = (float)pnn;
    float dn = (float)doneL[t * SQ + s];

    // (B) issue gi(t+1) loads (clamped dup at tail)
    if (t < kT - 1) gpl += cstep;
    prn = gpl[0];
    pzn = gpl[64];
    pnn = gpl[128];

    // (C) MFMA over K=256: A = h rows dup'd (sr); B: n,z from AGPR, r from LDS.
    // ss=0 uses hoisted C-in (Z / BN) -> no per-step acc init.
    f32x4 ar0, ar1, az0, az1, an0, an1;
    {
      const __bf16* hb = &hbuf[t & 1][0];
      const unsigned char* h8b = &h8buf[t & 1][0];
      {
        bf16x8 afr = *(const bf16x8*)(hb + sr * 288 + lg * 8);
        long   a8  = *(const long*)(h8b + sr * 288 + lg * 8);
        int4  brp = *(const int4*)(wrb + lane * 16);
        int2  b0i = {brp.x, brp.y};
        int2  b1i = {brp.z, brp.w};
        long  br0 = __builtin_bit_cast(long, b0i);
        long  br1 = __builtin_bit_cast(long, b1i);
        ar0 = __builtin_amdgcn_mfma_f32_16x16x32_fp8_fp8(a8, br0, Z, 0, 0, 0);
        ar1 = __builtin_amdgcn_mfma_f32_16x16x32_fp8_fp8(a8, br1, Z, 0, 0, 0);
        az0 = __builtin_amdgcn_mfma_f32_16x16x32_bf16(afr, __builtin_bit_cast(bf16x8, wfz[0]), Z, 0, 0, 0);
        az1 = __builtin_amdgcn_mfma_f32_16x16x32_bf16(afr, __builtin_bit_cast(bf16x8, wfz[8]), Z, 0, 0, 0);
        an0 = __builtin_amdgcn_mfma_f32_16x16x32_bf16(afr, __builtin_bit_cast(bf16x8, wfn[0]), BN0, 0, 0, 0);
        an1 = __builtin_amdgcn_mfma_f32_16x16x32_bf16(afr, __builtin_bit_cast(bf16x8, wfn[8]), BN1, 0, 0, 0);
      }
      #pragma unroll
      for (int ss = 1; ss < 8; ++ss) {
        bf16x8 afr = *(const bf16x8*)(hb + sr * 288 + ss * 32 + lg * 8);
        long   a8  = *(const long*)(h8b + sr * 288 + ss * 32 + lg * 8);
        int4  brp = *(const int4*)(wrb + (ss * 64 + lane) * 16);
        int2  b0i = {brp.x, brp.y};
        int2  b1i = {brp.z, brp.w};
        long  br0 = __builtin_bit_cast(long, b0i);
        long  br1 = __builtin_bit_cast(long, b1i);
        ar0 = __builtin_amdgcn_mfma_f32_16x16x32_fp8_fp8(a8, br0, ar0, 0, 0, 0);
        ar1 = __builtin_amdgcn_mfma_f32_16x16x32_fp8_fp8(a8, br1, ar1, 0, 0, 0);
        az0 = __builtin_amdgcn_mfma_f32_16x16x32_bf16(afr, __builtin_bit_cast(bf16x8, wfz[ss]),     az0, 0, 0, 0);
        az1 = __builtin_amdgcn_mfma_f32_16x16x32_bf16(afr, __builtin_bit_cast(bf16x8, wfz[8 + ss]), az1, 0, 0, 0);
        an0 = __builtin_amdgcn_mfma_f32_16x16x32_bf16(afr, __builtin_bit_cast(bf16x8, wfn[ss]),     an0, 0, 0, 0);
        an1 = __builtin_amdgcn_mfma_f32_16x16x32_bf16(afr, __builtin_bit_cast(bf16x8, wfn[8 + ss]), an1, 0, 0, 0);
      }
    }

    // (D) gates: each lane owns one h-element (s, jh); gi added as scalars.
    {
      __bf16* hw = &hbuf[(t & 1) ^ 1][0];
      unsigned char* h8w = &h8buf[(t & 1) ^ 1][0];
      float rv = sigm(gir + (ch ? sel01(ar1, s) : sel01(ar0, s)));
      float zv = sigm(giz + (ch ? sel01(az1, s) : sel01(az0, s)));
      float hv = ch ? sel01(an1, s) : sel01(an0, s);   // gh_n + b_hh_n (via BN)
      float nv = tanh_fast(gin + rv * hv);
      float hn = nv + zv * (hold - nv);
      float hk = hn * (1.0f - dn);
      hold = hk;
      *op = hn;
      hw[s * 288 + jh] = (__bf16)hk;
      int pk8 = __builtin_amdgcn_cvt_pk_fp8_f32(hk, hk, 0, 0);
      h8w[s * 288 + jh] = (unsigned char)(pk8 & 255);
    }
    op += (long)kN * kH;

    // (E) h(t+1) visible to all waves: LDS-only fence + raw barrier
    // (gi prefetch + out stores stay in flight across the barrier).
    asm volatile("s_waitcnt lgkmcnt(0)" ::: "memory");
    asm volatile("s_barrier" ::: "memory");
  }

  // final hidden state (doneL last row = 0, so hold == h_T); full-wave store
  {
    float* outF = out + (long)kT * kN * kH;
    outF[(long)(nb2 + s) * kH + jh] = hold;
  }
}

// ---------------------------------------------------------------------------
// Fallback (ws too small): naive fp32.
// ---------------------------------------------------------------------------
__global__ __launch_bounds__(256) void gru_naive(
    const float* __restrict__ x, const float* __restrict__ h0,
    const float* __restrict__ done, const float* __restrict__ Wih,
    const float* __restrict__ Whh, const float* __restrict__ bih,
    const float* __restrict__ bhh, float* __restrict__ out)
{
  __shared__ float hsA[16][257];
  __shared__ float hsB[16][257];
  const int tid = threadIdx.x;
  const int b = blockIdx.x, nb = b * 16;
  for (int s = 0; s < 16; ++s)
    hsA[s][tid] = h0[(long)(nb + s) * 256 + tid] * (1.0f - done[nb + s]);
  __syncthreads();
  float (*hr)[257] = hsA;
  float (*hw)[257] = hsB;
  float* outF = out + (long)kT * kN * kH;
  for (int t = 0; t < kT; ++t) {
    for (int s = 0; s < 16; ++s) {
      const float* xr = x + ((long)t * kN + nb + s) * 256;
      float pr  = bih[tid] + bhh[tid];
      float pz  = bih[256 + tid] + bhh[256 + tid];
      float pnx = bih[512 + tid];
      float pnh = bhh[512 + tid];
      const float* wr = Wih + (long)tid * 256;
      const float* wz = Wih + (long)(256 + tid) * 256;
      const float* wn = Wih + (long)(512 + tid) * 256;
      const float* vr = Whh + (long)tid * 256;
      const float* vz = Whh + (long)(256 + tid) * 256;
      const float* vn = Whh + (long)(512 + tid) * 256;
      #pragma unroll 4
      for (int k = 0; k < 256; ++k) {
        float xv = xr[k], hv = hr[s][k];
        pr  = fmaf(xv, wr[k], pr);  pr  = fmaf(hv, vr[k], pr);
        pz  = fmaf(xv, wz[k], pz);  pz  = fmaf(hv, vz[k], pz);
        pnx = fmaf(xv, wn[k], pnx); pnh = fmaf(hv, vn[k], pnh);
      }
      float r = sigm(pr), z = sigm(pz);
      float n = tanh_fast(pnx + r * pnh);
      float ho = hr[s][tid];
      float hn = n + z * (ho - n);
      out[((long)t * kN + nb + s) * 256 + tid] = hn;
      if (t == kT - 1) outF[(long)(nb + s) * 256 + tid] = hn;
      float d = (t < kT - 1) ? done[(long)(t + 1) * kN + nb + s] : 0.0f;
      hw[s][tid] = hn * (1.0f - d);
    }
    __syncthreads();
    float (*tmp)[257] = hr; hr = hw; hw = tmp;
  }
}

extern "C" void kernel_launch(void* const* d_in, const int* in_sizes, int n_in,
                              void* d_out, int out_size, void* d_ws, size_t ws_size,
                              hipStream_t stream) {
  const float* x    = (const float*)d_in[0];
  const float* h0   = (const float*)d_in[1];
  const float* done = (const float*)d_in[2];
  const float* Wih  = (const float*)d_in[3];
  const float* Whh  = (const float*)d_in[4];
  const float* bih  = (const float*)d_in[5];
  const float* bhh  = (const float*)d_in[6];
  float* out = (float*)d_out;

  const size_t GI_BYTES = (size_t)kT * kN * 768 * 2;  // 402.7 MB bf16
  if (ws_size >= GI_BYTES) {
    __bf16* gis = (__bf16*)d_ws;
    hipLaunchKernelGGL(gi_gemm, dim3(2048), dim3(512), 0, stream, x, Wih, bih, bhh, gis);
    hipLaunchKernelGGL(gru_scan, dim3(SBL), dim3(512), 0, stream, gis, h0, done, Whh, bhh, out);
  } else {
    hipLaunchKernelGGL(gru_naive, dim3(32), dim3(256), 0, stream, x, h0, done, Wih, Whh, bih, bhh, out);
  }
}